// Round 5
// baseline (2255.142 us; speedup 1.0000x reference)
//
#include <hip/hip_runtime.h>
#include <hip/hip_bf16.h>
#include <math.h>

#define NPTS 2048
#define KNB 64
#define SPC (KNB*NPTS)

typedef short bf16x8 __attribute__((ext_vector_type(8)));
typedef float f32x4 __attribute__((ext_vector_type(4)));

static __device__ inline short f2b(float f){ __hip_bfloat16 h = __float2bfloat16(f); short s; __builtin_memcpy(&s,&h,2); return s; }
static __device__ inline float b2f(short s){ __hip_bfloat16 h; __builtin_memcpy(&h,&s,2); return __bfloat162float(h); }

// ---------- weight convert fp32[O][Cs] -> bf16[O][Cd] (zero pad c>=Cs) ----------
__global__ __launch_bounds__(256) void cvt_w(const float* __restrict__ src, short* __restrict__ dst,
                                             int O, int Cs, int Cd)
{
  const int i = blockIdx.x*256 + threadIdx.x;
  if (i >= O*Cd) return;
  const int o = i / Cd, c = i % Cd;
  dst[i] = (c < Cs) ? f2b(src[o*Cs + c]) : (short)0;
}

__global__ __launch_bounds__(256) void fill0(float* __restrict__ p, int n)
{ const int i = blockIdx.x*256 + threadIdx.x; if (i < n) p[i] = 0.f; }

__global__ __launch_bounds__(256) void fillv(float* __restrict__ p, int n, float v)
{ const int i = blockIdx.x*256 + threadIdx.x; if (i < n) p[i] = v; }

// ---------- ball query, wave-parallel; FEATb[z][k*NPTS+m][8] bf16 ----------
__global__ __launch_bounds__(256) void bq_feat(const float* __restrict__ src,
                                               const float* __restrict__ tgt,
                                               short* __restrict__ featb)
{
  const int z = blockIdx.y;
  const float* xyz = (z < 2) ? src + (size_t)z*NPTS*3 : tgt + (size_t)(z-2)*NPTS*3;
  __shared__ float cs[NPTS*3];
  for (int i = threadIdx.x; i < NPTS*3; i += 256) cs[i] = xyz[i];
  __syncthreads();
  const int wave = threadIdx.x >> 6, lane = threadIdx.x & 63;
  const int m = blockIdx.x*4 + wave;
  short* fb = featb + (long long)z*SPC*8;
  const float px = cs[3*m], py = cs[3*m+1], pz = cs[3*m+2];
  const float sqm = __fadd_rn(__fadd_rn(__fmul_rn(px,px), __fmul_rn(py,py)), __fmul_rn(pz,pz));
  const short pxh = f2b(px), pyh = f2b(py), pzh = f2b(pz);
  int cnt = 0;
  float frx = 0.f, fry = 0.f, frz = 0.f;
  for (int r = 0; r < 32; ++r) {
    const int n = r*64 + lane;
    const float xn = cs[3*n], yn = cs[3*n+1], zn = cs[3*n+2];
    const float sqn = __fadd_rn(__fadd_rn(__fmul_rn(xn,xn), __fmul_rn(yn,yn)), __fmul_rn(zn,zn));
    const float dt  = __fadd_rn(__fadd_rn(__fmul_rn(px,xn), __fmul_rn(py,yn)), __fmul_rn(pz,zn));
    const float d   = __fsub_rn(__fadd_rn(sqm, sqn), __fmul_rn(2.0f, dt));
    const bool hit = (d <= 0.09f);
    const unsigned long long mask = __ballot(hit);
    const int pre = __popcll(mask & ((1ull << lane) - 1ull));
    const int slot = cnt + pre;
    const float rx = xn-px, ry = yn-py, rz = zn-pz;
    if (hit && slot < KNB) {
      short tmp[8] = {pxh, pyh, pzh, f2b(rx), f2b(ry), f2b(rz), 0, 0};
      uint4 raw; __builtin_memcpy(&raw, tmp, 16);
      *(uint4*)&fb[((long long)slot*NPTS + m)*8] = raw;
    }
    if (cnt == 0 && mask) {
      const int fl = __ffsll(mask) - 1;
      frx = __shfl(rx, fl); fry = __shfl(ry, fl); frz = __shfl(rz, fl);
    }
    cnt += __popcll(mask);
    if (cnt >= KNB) break;
  }
  if (cnt < KNB && lane < KNB - cnt) {
    const int slot = cnt + lane;
    short tmp[8] = {pxh, pyh, pzh, f2b(frx), f2b(fry), f2b(frz), 0, 0};
    uint4 raw; __builtin_memcpy(&raw, tmp, 16);
    *(uint4*)&fb[((long long)slot*NPTS + m)*8] = raw;
  }
}

// ---------- universal MFMA GEMM (tile 128s x 64o) ----------
template<int ABF16>
__global__ __launch_bounds__(256) void mm(
    const void* __restrict__ Ap, long long ldA, long long aZ,
    const float* __restrict__ A2, long long ldA2, long long a2Z,
    const short* __restrict__ Bw, long long bZ,
    void* __restrict__ outp, long long ldo, long long oZ, int outBf16,
    const float* __restrict__ bias,
    const float* __restrict__ rowScale, long long rsZ,
    const float* __restrict__ inStats, long long isZ,
    const float* __restrict__ inW, const float* __restrict__ inB,
    float* __restrict__ outPart, long long pZ, int grpCh,
    int N, int K, int S)
{
  constexpr int RP = 40;
  __shared__ __align__(16) short As[128*RP];
  __shared__ __align__(16) short Bs[64*RP];
  __shared__ float rowS[64], rowQ[64], gSs[4], gQs[4];
  const int tid = threadIdx.x;
  const int z = blockIdx.z;
  const int s_blk = blockIdx.x*128;
  const int o_blk = blockIdx.y*64;
  const int lane = tid & 63;
  const int widx = tid >> 6;
  const int w_s = widx & 1, w_o = widx >> 1;
  const int l15 = lane & 15, l4 = lane >> 4;

  const short* Bz = Bw + (long long)z*bZ;
  const float* stz = inStats ? inStats + (long long)z*isZ : nullptr;

  f32x4 acc[2][4];
  #pragma unroll
  for (int i = 0; i < 2; ++i)
    #pragma unroll
    for (int j = 0; j < 4; ++j) acc[i][j] = (f32x4){0.f,0.f,0.f,0.f};

  if (outPart) {
    if (tid < 64) { rowS[tid] = 0.f; rowQ[tid] = 0.f; }
    if (tid < 4)  { gSs[tid] = 0.f; gQs[tid] = 0.f; }
  }

  for (int c0 = 0; c0 < K; c0 += 32) {
    __syncthreads();
    #pragma unroll
    for (int it = 0; it < 2; ++it) {
      const int ch = tid + it*256;
      const int row = ch >> 2, cq = ch & 3;
      const int gc = c0 + cq*8;
      uint4 raw = make_uint4(0,0,0,0);
      if (gc < K) {
        const long long base = (long long)(s_blk+row)*ldA + gc;
        if (ABF16) {
          raw = *(const uint4*)((const short*)Ap + (long long)z*aZ + base);
          if (stz) {
            short vs[8]; __builtin_memcpy(vs, &raw, 16);
            const int g = gc >> 5;
            const float mu = stz[2*g], rsg = stz[2*g+1];
            short tmp[8];
            #pragma unroll
            for (int j = 0; j < 8; ++j) {
              const float v = (b2f(vs[j]) - mu)*rsg*inW[gc+j] + inB[gc+j];
              tmp[j] = f2b(fmaxf(v, 0.f));
            }
            __builtin_memcpy(&raw, tmp, 16);
          }
        } else {
          const float* Af = (const float*)Ap + (long long)z*aZ + base;
          float4 u0 = *(const float4*)Af;
          float4 u1 = *(const float4*)(Af + 4);
          if (A2) {
            const float* Sf = A2 + (long long)z*a2Z + (long long)(s_blk+row)*ldA2 + gc;
            const float4 s0 = *(const float4*)Sf, s1 = *(const float4*)(Sf + 4);
            u0.x -= s0.x; u0.y -= s0.y; u0.z -= s0.z; u0.w -= s0.w;
            u1.x -= s1.x; u1.y -= s1.y; u1.z -= s1.z; u1.w -= s1.w;
          }
          short tmp[8] = {f2b(u0.x),f2b(u0.y),f2b(u0.z),f2b(u0.w),
                          f2b(u1.x),f2b(u1.y),f2b(u1.z),f2b(u1.w)};
          __builtin_memcpy(&raw, tmp, 16);
        }
      }
      *(uint4*)&As[row*RP + cq*8] = raw;
    }
    {
      const int row = tid >> 2, cq = tid & 3;
      const int gc = c0 + cq*8, go = o_blk + row;
      uint4 raw = make_uint4(0,0,0,0);
      if (go < N && gc < K)
        raw = *(const uint4*)(Bz + (long long)go*K + gc);
      *(uint4*)&Bs[row*RP + cq*8] = raw;
    }
    __syncthreads();
    bf16x8 af[4], bfr[2];
    #pragma unroll
    for (int ts = 0; ts < 4; ++ts)
      af[ts] = *(const bf16x8*)&As[(w_s*64 + ts*16 + l15)*RP + l4*8];
    #pragma unroll
    for (int to = 0; to < 2; ++to)
      bfr[to] = *(const bf16x8*)&Bs[(w_o*32 + to*16 + l15)*RP + l4*8];
    #pragma unroll
    for (int to = 0; to < 2; ++to)
      #pragma unroll
      for (int ts = 0; ts < 4; ++ts)
        acc[to][ts] = __builtin_amdgcn_mfma_f32_16x16x32_bf16(af[ts], bfr[to], acc[to][ts], 0, 0, 0);
  }

  const int s_base = s_blk + w_s*64;
  const int o_base = o_blk + w_o*32;
  float* ozF = (float*)outp + (long long)z*oZ;
  short* ozH = (short*)outp + (long long)z*oZ;
  #pragma unroll
  for (int to = 0; to < 2; ++to) {
    const int o = o_base + to*16 + l15;
    const bool ov = (o < N);
    const float bv = (bias && ov) ? bias[o] : 0.f;
    float ps = 0.f, pq = 0.f;
    #pragma unroll
    for (int ts = 0; ts < 4; ++ts) {
      #pragma unroll
      for (int r = 0; r < 4; ++r) {
        const int s = s_base + ts*16 + l4*4 + r;
        float v = acc[to][ts][r] + bv;
        if (rowScale) v *= rowScale[(long long)z*rsZ + s];
        if (ov) {
          if (outBf16) ozH[(long long)s*ldo + o] = f2b(v);
          else         ozF[(long long)s*ldo + o] = v;
          ps += v; pq = fmaf(v, v, pq);
        }
      }
    }
    if (outPart) {
      ps += __shfl_down(ps, 32); pq += __shfl_down(pq, 32);
      ps += __shfl_down(ps, 16); pq += __shfl_down(pq, 16);
      if (lane < 16) {
        atomicAdd(&rowS[w_o*32 + to*16 + l15], ps);
        atomicAdd(&rowQ[w_o*32 + to*16 + l15], pq);
      }
    }
  }
  if (outPart) {
    __syncthreads();
    if (tid < 64) {
      const int o = o_blk + tid;
      if (o < N) {
        const int gl = o/grpCh - o_blk/grpCh;
        atomicAdd(&gSs[gl], rowS[tid]);
        atomicAdd(&gQs[gl], rowQ[tid]);
      }
    }
    __syncthreads();
    const int g0 = o_blk/grpCh;
    const int hi = (o_blk + 63 < N - 1) ? o_blk + 63 : N - 1;
    if (tid <= hi/grpCh - g0) {
      float* pp = outPart + (long long)z*pZ;
      atomicAdd(&pp[2*(g0+tid)],   gSs[tid]);
      atomicAdd(&pp[2*(g0+tid)+1], gQs[tid]);
    }
  }
}

// ---------- fused QK^T + softmax, writes transposed bf16 att ----------
// block: 64 query rows (4 waves x 16 rows); loops 32 key-tiles of 64, twice:
// pass0 = online (max,sum) per row; pass1 = write exp(s-max)/sum to ATTB[m][n].
__global__ __launch_bounds__(256) void attn_fused(
    const short* __restrict__ qkt,   // [z][NPTS][48] bf16
    short* __restrict__ attb)        // [z][m][n] bf16
{
  constexpr int QP = 72;  // LDS row pitch (shorts): 48 data + zero pad
  __shared__ __align__(16) short Qs[64*QP];
  __shared__ __align__(16) short Ks[64*QP];
  const int tid = threadIdx.x;
  const int z = blockIdx.y;
  const int n0 = blockIdx.x * 64;
  const int w = tid >> 6, lane = tid & 63;
  const int l15 = lane & 15, l4 = lane >> 4;
  const short* qz = qkt + (long long)z*NPTS*48;
  short* az = attb + (long long)z*NPTS*NPTS;

  for (int idx = tid; idx < 64*9; idx += 256) {
    const int row = idx/9, q = idx%9;
    uint4 raw = make_uint4(0,0,0,0);
    if (q < 6) raw = *(const uint4*)&qz[(n0+row)*48 + q*8];
    *(uint4*)&Qs[row*QP + q*8] = raw;
  }

  float rmax[4], rsum[4], rinv[4];
  #pragma unroll
  for (int r = 0; r < 4; ++r) { rmax[r] = -1e30f; rsum[r] = 0.f; }

  #pragma unroll 1
  for (int pass = 0; pass < 2; ++pass) {
    if (pass == 1) {
      #pragma unroll
      for (int r = 0; r < 4; ++r) rinv[r] = 1.0f / rsum[r];
    }
    #pragma unroll 1
    for (int mt = 0; mt < 32; ++mt) {
      __syncthreads();
      for (int idx = tid; idx < 64*9; idx += 256) {
        const int row = idx/9, q = idx%9;
        uint4 raw = make_uint4(0,0,0,0);
        if (q < 6) raw = *(const uint4*)&qz[(mt*64+row)*48 + q*8];
        *(uint4*)&Ks[row*QP + q*8] = raw;
      }
      __syncthreads();
      f32x4 acc[4];
      #pragma unroll
      for (int to = 0; to < 4; ++to) acc[to] = (f32x4){0.f,0.f,0.f,0.f};
      #pragma unroll
      for (int c0 = 0; c0 < 64; c0 += 32) {
        const bf16x8 af = *(const bf16x8*)&Qs[(w*16+l15)*QP + c0 + l4*8];
        #pragma unroll
        for (int to = 0; to < 4; ++to) {
          const bf16x8 bfr = *(const bf16x8*)&Ks[(to*16+l15)*QP + c0 + l4*8];
          acc[to] = __builtin_amdgcn_mfma_f32_16x16x32_bf16(af, bfr, acc[to], 0, 0, 0);
        }
      }
      if (pass == 0) {
        #pragma unroll
        for (int r = 0; r < 4; ++r) {
          float tmax = fmaxf(fmaxf(acc[0][r], acc[1][r]), fmaxf(acc[2][r], acc[3][r]));
          tmax = fmaxf(tmax, __shfl_xor(tmax, 1));
          tmax = fmaxf(tmax, __shfl_xor(tmax, 2));
          tmax = fmaxf(tmax, __shfl_xor(tmax, 4));
          tmax = fmaxf(tmax, __shfl_xor(tmax, 8));
          const float mnew = fmaxf(rmax[r], tmax);
          float p = expf(acc[0][r]-mnew) + expf(acc[1][r]-mnew)
                  + expf(acc[2][r]-mnew) + expf(acc[3][r]-mnew);
          p += __shfl_xor(p, 1); p += __shfl_xor(p, 2);
          p += __shfl_xor(p, 4); p += __shfl_xor(p, 8);
          rsum[r] = rsum[r]*expf(rmax[r]-mnew) + p;
          rmax[r] = mnew;
        }
      } else {
        #pragma unroll
        for (int to = 0; to < 4; ++to) {
          short v4[4];
          #pragma unroll
          for (int r = 0; r < 4; ++r)
            v4[r] = f2b(expf(acc[to][r] - rmax[r]) * rinv[r]);
          const int m = mt*64 + to*16 + l15;
          uint2 raw; __builtin_memcpy(&raw, v4, 8);
          *(uint2*)&az[(long long)m*NPTS + n0 + w*16 + l4*4] = raw;
        }
      }
    }
  }
}

// ---------- finalize GN stats ----------
__global__ void fin_stats(float* __restrict__ part, float* __restrict__ stats,
                          long long slotStride, int G, float invGS)
{
  const int g = threadIdx.x;
  float* p  = part  + (long long)blockIdx.x * slotStride;
  float* st = stats + (long long)blockIdx.x * slotStride;
  if (g < G) {
    const float mu  = p[2*g] * invGS;
    const float var = p[2*g+1] * invGS - mu*mu;
    st[2*g]   = mu;
    st[2*g+1] = rsqrtf(var + 1e-5f);
    p[2*g] = 0.f; p[2*g+1] = 0.f;
  }
}

// ---------- maxpool accumulate ----------
__global__ __launch_bounds__(192) void maxpool_racc(const short* __restrict__ c3t, int kc,
                                                    long long c3Z, float* __restrict__ pool)
{
  const int n = blockIdx.x, z = blockIdx.y, c = threadIdx.x;
  const short* b = c3t + (long long)z*c3Z;
  float m = -1e30f;
  for (int r = 0; r < kc; ++r)
    m = fmaxf(m, b2f(b[((long long)r*NPTS + n)*192 + c]));
  float* p = &pool[((long long)z*NPTS + n)*192 + c];
  *p = fmaxf(*p, m);
}

// ---------- gn+relu on POOLt [4][NPTS][192] ----------
__global__ __launch_bounds__(256) void gn_pool(float* __restrict__ pool,
    const float* __restrict__ stats, const float* __restrict__ w, const float* __restrict__ b)
{
  const int i = blockIdx.x*256 + threadIdx.x;
  const int z = i / (NPTS*192);
  const int c = i % 192;
  const int g = c >> 5;
  const float* st = stats + z*64;
  const float v = (pool[i] - st[2*g]) * st[2*g+1] * w[c] + b[c];
  pool[i] = fmaxf(v, 0.f);
}

// ---------- FEATS slot[n][c] = xin[n][c] + relu(gn(t[n][c])) ----------
__global__ __launch_bounds__(256) void gn_resid(const float* __restrict__ t,
    const float* __restrict__ xin, long long xZ, long long xld,
    const float* __restrict__ stats,
    const float* __restrict__ w, const float* __restrict__ b,
    float* __restrict__ outp, long long oZ)
{
  const int i = blockIdx.x*256 + threadIdx.x;
  const int z = blockIdx.y;
  const int n = i / 192, c = i % 192, g = c >> 5;
  const float* st = stats + z*16;
  const float v = (t[(long long)z*NPTS*192 + i] - st[2*g]) * st[2*g+1] * w[c] + b[c];
  outp[(long long)z*oZ + (long long)n*768 + c] =
      xin[(long long)z*xZ + (long long)n*xld + c] + fmaxf(v, 0.f);
}

// ---------- transpose -> bf16: src[z][R][C] -> dst[z][C][R] ----------
template<int SRCF32>
__global__ __launch_bounds__(256) void tr2bf(const void* __restrict__ src, short* __restrict__ dst,
                                             long long sZ, long long dZ, int R, int C)
{
  __shared__ float t[32][33];
  const int z = blockIdx.z;
  const int c0 = blockIdx.x*32, r0 = blockIdx.y*32;
  const int tx = threadIdx.x % 32, ty = threadIdx.x / 32;
  #pragma unroll
  for (int j = 0; j < 4; ++j) {
    const int r = r0 + ty + j*8;
    const long long idx = (long long)z*sZ + (long long)r*C + c0 + tx;
    t[ty + j*8][tx] = SRCF32 ? ((const float*)src)[idx] : b2f(((const short*)src)[idx]);
  }
  __syncthreads();
  #pragma unroll
  for (int j = 0; j < 4; ++j) {
    const int c = c0 + ty + j*8;
    dst[(long long)z*dZ + (long long)c*R + r0 + tx] = f2b(t[tx][ty + j*8]);
  }
}

// ---------- per-row sums of ATTB [z][m][n] -> SINV[z][m] = 1/(1e-9+sum) ----------
__global__ __launch_bounds__(256) void colsum_rows(const short* __restrict__ attb,
                                                   float* __restrict__ sinv)
{
  const int wave = threadIdx.x >> 6, lane = threadIdx.x & 63;
  const int m = blockIdx.x*4 + wave, z = blockIdx.y;
  const short* row = attb + (long long)z*NPTS*NPTS + (long long)m*NPTS;
  float s = 0.f;
  for (int j = 0; j < NPTS/64; ++j) s += b2f(row[lane + j*64]);
  s += __shfl_down(s, 32); s += __shfl_down(s, 16);
  s += __shfl_down(s, 8);  s += __shfl_down(s, 4);
  s += __shfl_down(s, 2);  s += __shfl_down(s, 1);
  if (lane == 0) sinv[z*NPTS + m] = 1.0f / (1e-9f + s);
}

// ---------- fuse epilogue: GN(16x48) + leaky(0.2) + L2 norm ----------
__global__ __launch_bounds__(256) void finalize_gn(const float* __restrict__ fused,
    const float* __restrict__ stats, const float* __restrict__ w, const float* __restrict__ b,
    float* __restrict__ outp, long long oZ)
{
  const int n = blockIdx.x, z = blockIdx.y, tid = threadIdx.x;
  const float* fz = fused + ((long long)z*NPTS + n)*768;
  const float* st = stats + z*32;
  __shared__ float vbuf[768];
  __shared__ float red[256];
  float ss = 0.f;
  for (int c = tid; c < 768; c += 256) {
    float v = fz[c];
    const int g = c / 48;
    v = (v - st[2*g]) * st[2*g+1] * w[c] + b[c];
    v = v > 0.f ? v : 0.2f * v;
    vbuf[c] = v;
    ss = fmaf(v, v, ss);
  }
  red[tid] = ss; __syncthreads();
  for (int st_ = 128; st_; st_ >>= 1) { if (tid < st_) red[tid] += red[tid+st_]; __syncthreads(); }
  const float inv = 1.0f / (sqrtf(red[0]) + 1e-8f);
  float* ob = outp + (long long)z*oZ + (long long)n*768;
  for (int c = tid; c < 768; c += 256) ob[c] = vbuf[c] * inv;
}

extern "C" void kernel_launch(void* const* d_in, const int* in_sizes, int n_in,
                              void* d_out, int out_size, void* d_ws, size_t ws_size,
                              hipStream_t stream)
{
  const float* src = (const float*)d_in[0];
  const float* tgt = (const float*)d_in[1];
  const float* lfw[3]  = {(const float*)d_in[5], (const float*)d_in[8],  (const float*)d_in[11]};
  const float* lfgw[3] = {(const float*)d_in[6], (const float*)d_in[9],  (const float*)d_in[12]};
  const float* lfgb[3] = {(const float*)d_in[7], (const float*)d_in[10], (const float*)d_in[13]};
  const float* qk_w = (const float*)d_in[14];
  const float* v_w  = (const float*)d_in[15];
  const float* v_b  = (const float*)d_in[16];
  const float* t_w  = (const float*)d_in[17];
  const float* t_b  = (const float*)d_in[18];
  const float* bgw  = (const float*)d_in[19];
  const float* bgb  = (const float*)d_in[20];
  const float* fw   = (const float*)d_in[21];
  const float* fgw  = (const float*)d_in[22];
  const float* fgb  = (const float*)d_in[23];
  float* dout = (float*)d_out;

  const size_t availFl = ws_size / sizeof(float);
  float* ws = (float*)d_ws;
  size_t off = 0;
  float* POOLt = ws + off; off += (size_t)4*NPTS*192;     // [4][n][192]
  float* PART  = ws + off; off += 1024;
  float* STATS = ws + off; off += 1024;
  float* SINV  = ws + off; off += (size_t)4*NPTS;
  // bf16 weights
  short* wreg = (short*)(ws + off);
  short* lfw0b = wreg;              // 128x8
  short* lfw1b = lfw0b + 1024;      // 256x128
  short* lfw2b = lfw1b + 32768;     // 192x256
  short* qkwb  = lfw2b + 49152;     // 4x48x192
  short* vwb   = qkwb + 36864;      // 4x192x192
  short* twb   = vwb + 147456;      // 4x192x192
  short* fwb   = twb + 147456;      // 768x768
  off += (1024+32768+49152+36864+147456+147456+589824 + 1)/2 + 8;
  short* FEATb = (short*)(ws + off); off += (size_t)4*SPC*8/2;  // [4][k*NPTS+m][8]
  off = (off + 63) & ~(size_t)63;
  float* REG = ws + off;
  const size_t regAvail = (availFl > off) ? (availFl - off) : 0;

  // attention batching: floats per z = XRt+Tt+FUSED + (QKT+Vt+Vc)/2 + ATTB/2
  const size_t perZ = 4898816;
  int nz;
  if      (regAvail >= 4*perZ) nz = 4;
  else if (regAvail >= 2*perZ) nz = 2;
  else if (regAvail >= perZ)   nz = 1;
  else return;
  // conv chunking (z=4 batched): floats = 2,359,296 * kc
  int kc = 0;
  for (int cand = 64; cand >= 1; cand >>= 1)
    if ((size_t)2359296*cand <= regAvail) { kc = cand; break; }
  if (!kc) return;
  const int Sc = kc * NPTS;
  const int nChunks = KNB / kc;

  // conv view of REG
  short* C1t = (short*)REG;                         // [4][Sc][128]
  short* C2t = C1t + (size_t)4*Sc*128;              // [4][Sc][256]
  short* C3t = C2t + (size_t)4*Sc*256;              // [4][Sc][192]
  // attn view of REG
  float* XRt   = REG;                               // [nz][n][192]
  float* Tt    = XRt + (size_t)nz*NPTS*192;         // [nz][n][192]
  float* FUSED = Tt  + (size_t)nz*NPTS*192;         // [nz][n][768]
  short* QKT   = (short*)(FUSED + (size_t)nz*NPTS*768);  // [nz][n][48]
  short* Vt    = QKT + (size_t)nz*NPTS*48;          // [nz][n][192]
  short* Vc    = Vt  + (size_t)nz*NPTS*192;         // [nz][192][n]
  short* ATTB  = Vc  + (size_t)nz*NPTS*192;         // [nz][m][n]

  dim3 b256(256);
  const float invConv = 1.0f / (32.0f * (float)SPC);

  cvt_w<<<dim3(4),   b256, 0, stream>>>(lfw[0], lfw0b, 128, 6, 8);
  cvt_w<<<dim3(128), b256, 0, stream>>>(lfw[1], lfw1b, 256, 128, 128);
  cvt_w<<<dim3(192), b256, 0, stream>>>(lfw[2], lfw2b, 192, 256, 256);
  cvt_w<<<dim3(144), b256, 0, stream>>>(qk_w, qkwb, 192, 192, 192);
  cvt_w<<<dim3(576), b256, 0, stream>>>(v_w,  vwb,  768, 192, 192);
  cvt_w<<<dim3(576), b256, 0, stream>>>(t_w,  twb,  768, 192, 192);
  cvt_w<<<dim3(2304),b256, 0, stream>>>(fw,   fwb,  768, 768, 768);
  fill0<<<dim3(4), b256, 0, stream>>>(PART, 1024);

  // ---- ball query ----
  bq_feat<<<dim3(NPTS/4, 4), b256, 0, stream>>>(src, tgt, FEATb);

  // ---- conv stage, z=4 batched, chunked with recompute if needed ----
  for (int ck = 0; ck < nChunks; ++ck)
    mm<1><<<dim3(Sc/128, 2, 4), b256, 0, stream>>>(
        FEATb + (size_t)ck*Sc*8, 8, (long long)SPC*8, nullptr,0,0,
        lfw0b, 0, C1t, 128, (long long)Sc*128, 1,
        nullptr, nullptr,0, nullptr,0,nullptr,nullptr,
        PART, 64, 32, 128, 8, Sc);
  fin_stats<<<4, 32, 0, stream>>>(PART, STATS, 64, 4, invConv);
  for (int ck = 0; ck < nChunks; ++ck) {
    if (nChunks > 1)
      mm<1><<<dim3(Sc/128, 2, 4), b256, 0, stream>>>(
          FEATb + (size_t)ck*Sc*8, 8, (long long)SPC*8, nullptr,0,0,
          lfw0b, 0, C1t, 128, (long long)Sc*128, 1,
          nullptr, nullptr,0, nullptr,0,nullptr,nullptr,
          nullptr, 0, 1, 128, 8, Sc);
    mm<1><<<dim3(Sc/128, 4, 4), b256, 0, stream>>>(
        C1t, 128, (long long)Sc*128, nullptr,0,0,
        lfw1b, 0, C2t, 256, (long long)Sc*256, 1,
        nullptr, nullptr,0, STATS,64, lfgw[0], lfgb[0],
        PART+256, 64, 32, 256, 128, Sc);
  }
  fin_stats<<<4, 32, 0, stream>>>(PART+256, STATS+256, 64, 8, invConv);
  fillv<<<dim3(4*NPTS*192/256), b256, 0, stream>>>(POOLt, 4*NPTS*192, -1e30f);
  for (int ck = 0; ck < nChunks; ++ck) {
    if (nChunks > 1) {
      mm<1><<<dim3(Sc/128, 2, 4), b256, 0, stream>>>(
          FEATb + (size_t)ck*Sc*8, 8, (long long)SPC*8, nullptr,0,0,
          lfw0b, 0, C1t, 128, (long long)Sc*128, 1,
          nullptr, nullptr,0, nullptr,0,nullptr,nullptr,
          nullptr, 0, 1, 128, 8, Sc);
      mm<1><<<dim3(Sc/128, 4, 4), b256, 0, stream>>>(
          C1t, 128, (long long)Sc*128, nullptr,0,0,
          lfw1b, 0, C2t, 256, (long long)Sc*256, 1,
          nullptr, nullptr,0, STATS,64, lfgw[0], lfgb[0],
          nullptr, 0, 1, 256, 128, Sc);
    }
    mm<1><<<dim3(Sc/128, 3, 4), b256, 0, stream>>>(
        C2t, 256, (long long)Sc*256, nullptr,0,0,
        lfw2b, 0, C3t, 192, (long long)Sc*192, 1,
        nullptr, nullptr,0, STATS+256,64, lfgw[1], lfgb[1],
        PART+512, 64, 32, 192, 256, Sc);
    maxpool_racc<<<dim3(NPTS, 4), dim3(192), 0, stream>>>(C3t, kc, (long long)Sc*192, POOLt);
  }
  fin_stats<<<4, 32, 0, stream>>>(PART+512, STATS+512, 64, 6, invConv);
  gn_pool<<<dim3(4*NPTS*192/256), b256, 0, stream>>>(POOLt, STATS+512, lfgw[2], lfgb[2]);

  // ---- attention + fuse, nz clouds per batch ----
  for (int bb0 = 0; bb0 < 4; bb0 += nz) {
    for (int i = 0; i < 4; ++i) {
      const float* Xin; long long xZ, xld;
      if (i == 0) { Xin = POOLt + (size_t)bb0*NPTS*192; xZ = (long long)NPTS*192; xld = 192; }
      else        { Xin = dout + (size_t)bb0*NPTS*768 + (size_t)(i-1)*192; xZ = (long long)NPTS*768; xld = 768; }
      // qk -> QKT [n][48] bf16
      mm<0><<<dim3(16, 1, nz), b256, 0, stream>>>(
          Xin, xld, xZ, nullptr,0,0,
          qkwb + (size_t)i*48*192, 0, QKT, 48, (long long)NPTS*48, 1,
          nullptr, nullptr,0, nullptr,0,nullptr,nullptr,
          nullptr, 0, 1, 48, 192, NPTS);
      // v -> Vt [n][192] bf16 (+bias)
      mm<0><<<dim3(16, 3, nz), b256, 0, stream>>>(
          Xin, xld, xZ, nullptr,0,0,
          vwb + (size_t)i*192*192, 0, Vt, 192, (long long)NPTS*192, 1,
          v_b + (size_t)i*192, nullptr,0, nullptr,0,nullptr,nullptr,
          nullptr, 0, 1, 192, 192, NPTS);
      // fused QK^T + softmax -> ATTB bf16 [m][n]
      attn_fused<<<dim3(NPTS/64, nz), b256, 0, stream>>>(QKT, ATTB);
      colsum_rows<<<dim3(NPTS/4, nz), b256, 0, stream>>>(ATTB, SINV);
      tr2bf<0><<<dim3(6, 64, nz), b256, 0, stream>>>(Vt, Vc,
          (long long)NPTS*192, (long long)192*NPTS, NPTS, 192);
      // x_r^T [m][192] = (ATTB . Vc^T) * sinv[m]
      mm<1><<<dim3(16, 3, nz), b256, 0, stream>>>(
          ATTB, NPTS, (long long)NPTS*NPTS, nullptr,0,0,
          Vc, (long long)192*NPTS, XRt, 192, (long long)NPTS*192, 0,
          nullptr, SINV, NPTS, nullptr,0,nullptr,nullptr,
          nullptr, 0, 1, 192, NPTS, NPTS);
      // t [n][192] = (x - x_r) . t_w^T + t_b, + stats
      mm<0><<<dim3(16, 3, nz), b256, 0, stream>>>(
          Xin, xld, xZ, XRt, 192, (long long)NPTS*192,
          twb + (size_t)i*192*192, 0, Tt, 192, (long long)NPTS*192, 0,
          t_b + (size_t)i*192, nullptr,0, nullptr,0,nullptr,nullptr,
          PART+768, 16, 32, 192, 192, NPTS);
      fin_stats<<<nz, 32, 0, stream>>>(PART+768, STATS+768, 16, 6, 1.0f/65536.0f);
      gn_resid<<<dim3(NPTS*192/256, nz), b256, 0, stream>>>(
          Tt, Xin, xZ, xld, STATS+768,
          bgw + (size_t)i*192, bgb + (size_t)i*192,
          dout + (size_t)bb0*NPTS*768 + (size_t)i*192, (long long)NPTS*768);
    }
    // fuse
    mm<0><<<dim3(16, 12, nz), b256, 0, stream>>>(
        dout + (size_t)bb0*NPTS*768, 768, (long long)NPTS*768, nullptr,0,0,
        fwb, 0, FUSED, 768, (long long)NPTS*768, 0,
        nullptr, nullptr,0, nullptr,0,nullptr,nullptr,
        PART+832, 32, 48, 768, 768, NPTS);
    fin_stats<<<nz, 32, 0, stream>>>(PART+832, STATS+832, 32, 16, 1.0f/98304.0f);
    finalize_gn<<<dim3(NPTS, nz), b256, 0, stream>>>(
        FUSED, STATS+832, fgw, fgb,
        dout + (size_t)bb0*NPTS*768, (long long)NPTS*768);
  }
}

// Round 6
// 1900.863 us; speedup vs baseline: 1.1864x; 1.1864x over previous
//
#include <hip/hip_runtime.h>
#include <hip/hip_bf16.h>
#include <math.h>

#define NPTS 2048
#define KNB 64
#define SPC (KNB*NPTS)

typedef short bf16x8 __attribute__((ext_vector_type(8)));
typedef float f32x4 __attribute__((ext_vector_type(4)));

static __device__ inline short f2b(float f){ __hip_bfloat16 h = __float2bfloat16(f); short s; __builtin_memcpy(&s,&h,2); return s; }
static __device__ inline float b2f(short s){ __hip_bfloat16 h; __builtin_memcpy(&h,&s,2); return __bfloat162float(h); }

// ---------- weight convert fp32[O][Cs] -> bf16[O][Cd] (zero pad c>=Cs) ----------
__global__ __launch_bounds__(256) void cvt_w(const float* __restrict__ src, short* __restrict__ dst,
                                             int O, int Cs, int Cd)
{
  const int i = blockIdx.x*256 + threadIdx.x;
  if (i >= O*Cd) return;
  const int o = i / Cd, c = i % Cd;
  dst[i] = (c < Cs) ? f2b(src[o*Cs + c]) : (short)0;
}

__global__ __launch_bounds__(256) void fill0(float* __restrict__ p, int n)
{ const int i = blockIdx.x*256 + threadIdx.x; if (i < n) p[i] = 0.f; }

__global__ __launch_bounds__(256) void fillv(float* __restrict__ p, int n, float v)
{ const int i = blockIdx.x*256 + threadIdx.x; if (i < n) p[i] = v; }

// ---------- ball query, wave-parallel; FEATb[z][k*NPTS+m][8] bf16 ----------
__global__ __launch_bounds__(256) void bq_feat(const float* __restrict__ src,
                                               const float* __restrict__ tgt,
                                               short* __restrict__ featb)
{
  const int z = blockIdx.y;
  const float* xyz = (z < 2) ? src + (size_t)z*NPTS*3 : tgt + (size_t)(z-2)*NPTS*3;
  __shared__ float cs[NPTS*3];
  for (int i = threadIdx.x; i < NPTS*3; i += 256) cs[i] = xyz[i];
  __syncthreads();
  const int wave = threadIdx.x >> 6, lane = threadIdx.x & 63;
  const int m = blockIdx.x*4 + wave;
  short* fb = featb + (long long)z*SPC*8;
  const float px = cs[3*m], py = cs[3*m+1], pz = cs[3*m+2];
  const float sqm = __fadd_rn(__fadd_rn(__fmul_rn(px,px), __fmul_rn(py,py)), __fmul_rn(pz,pz));
  const short pxh = f2b(px), pyh = f2b(py), pzh = f2b(pz);
  int cnt = 0;
  float frx = 0.f, fry = 0.f, frz = 0.f;
  for (int r = 0; r < 32; ++r) {
    const int n = r*64 + lane;
    const float xn = cs[3*n], yn = cs[3*n+1], zn = cs[3*n+2];
    const float sqn = __fadd_rn(__fadd_rn(__fmul_rn(xn,xn), __fmul_rn(yn,yn)), __fmul_rn(zn,zn));
    const float dt  = __fadd_rn(__fadd_rn(__fmul_rn(px,xn), __fmul_rn(py,yn)), __fmul_rn(pz,zn));
    const float d   = __fsub_rn(__fadd_rn(sqm, sqn), __fmul_rn(2.0f, dt));
    const bool hit = (d <= 0.09f);
    const unsigned long long mask = __ballot(hit);
    const int pre = __popcll(mask & ((1ull << lane) - 1ull));
    const int slot = cnt + pre;
    const float rx = xn-px, ry = yn-py, rz = zn-pz;
    if (hit && slot < KNB) {
      short tmp[8] = {pxh, pyh, pzh, f2b(rx), f2b(ry), f2b(rz), 0, 0};
      uint4 raw; __builtin_memcpy(&raw, tmp, 16);
      *(uint4*)&fb[((long long)slot*NPTS + m)*8] = raw;
    }
    if (cnt == 0 && mask) {
      const int fl = __ffsll(mask) - 1;
      frx = __shfl(rx, fl); fry = __shfl(ry, fl); frz = __shfl(rz, fl);
    }
    cnt += __popcll(mask);
    if (cnt >= KNB) break;
  }
  if (cnt < KNB && lane < KNB - cnt) {
    const int slot = cnt + lane;
    short tmp[8] = {pxh, pyh, pzh, f2b(frx), f2b(fry), f2b(frz), 0, 0};
    uint4 raw; __builtin_memcpy(&raw, tmp, 16);
    *(uint4*)&fb[((long long)slot*NPTS + m)*8] = raw;
  }
}

// ---------- universal MFMA GEMM (tile 128s x 64o) ----------
template<int ABF16>
__global__ __launch_bounds__(256) void mm(
    const void* __restrict__ Ap, long long ldA, long long aZ,
    const float* __restrict__ A2, long long ldA2, long long a2Z,
    const short* __restrict__ Bw, long long bZ,
    void* __restrict__ outp, long long ldo, long long oZ, int outBf16,
    const float* __restrict__ bias,
    const float* __restrict__ rowScale, long long rsZ,
    const float* __restrict__ inStats, long long isZ,
    const float* __restrict__ inW, const float* __restrict__ inB,
    float* __restrict__ outPart, long long pZ, int grpCh,
    int N, int K, int S)
{
  constexpr int RP = 40;
  __shared__ __align__(16) short As[128*RP];
  __shared__ __align__(16) short Bs[64*RP];
  __shared__ float rowS[64], rowQ[64], gSs[4], gQs[4];
  const int tid = threadIdx.x;
  const int z = blockIdx.z;
  const int s_blk = blockIdx.x*128;
  const int o_blk = blockIdx.y*64;
  const int lane = tid & 63;
  const int widx = tid >> 6;
  const int w_s = widx & 1, w_o = widx >> 1;
  const int l15 = lane & 15, l4 = lane >> 4;

  const short* Bz = Bw + (long long)z*bZ;
  const float* stz = inStats ? inStats + (long long)z*isZ : nullptr;

  f32x4 acc[2][4];
  #pragma unroll
  for (int i = 0; i < 2; ++i)
    #pragma unroll
    for (int j = 0; j < 4; ++j) acc[i][j] = (f32x4){0.f,0.f,0.f,0.f};

  if (outPart) {
    if (tid < 64) { rowS[tid] = 0.f; rowQ[tid] = 0.f; }
    if (tid < 4)  { gSs[tid] = 0.f; gQs[tid] = 0.f; }
  }

  for (int c0 = 0; c0 < K; c0 += 32) {
    __syncthreads();
    #pragma unroll
    for (int it = 0; it < 2; ++it) {
      const int ch = tid + it*256;
      const int row = ch >> 2, cq = ch & 3;
      const int gc = c0 + cq*8;
      uint4 raw = make_uint4(0,0,0,0);
      if (gc < K) {
        const long long base = (long long)(s_blk+row)*ldA + gc;
        if (ABF16) {
          raw = *(const uint4*)((const short*)Ap + (long long)z*aZ + base);
          if (stz) {
            short vs[8]; __builtin_memcpy(vs, &raw, 16);
            const int g = gc >> 5;
            const float mu = stz[2*g], rsg = stz[2*g+1];
            short tmp[8];
            #pragma unroll
            for (int j = 0; j < 8; ++j) {
              const float v = (b2f(vs[j]) - mu)*rsg*inW[gc+j] + inB[gc+j];
              tmp[j] = f2b(fmaxf(v, 0.f));
            }
            __builtin_memcpy(&raw, tmp, 16);
          }
        } else {
          const float* Af = (const float*)Ap + (long long)z*aZ + base;
          float4 u0 = *(const float4*)Af;
          float4 u1 = *(const float4*)(Af + 4);
          if (A2) {
            const float* Sf = A2 + (long long)z*a2Z + (long long)(s_blk+row)*ldA2 + gc;
            const float4 s0 = *(const float4*)Sf, s1 = *(const float4*)(Sf + 4);
            u0.x -= s0.x; u0.y -= s0.y; u0.z -= s0.z; u0.w -= s0.w;
            u1.x -= s1.x; u1.y -= s1.y; u1.z -= s1.z; u1.w -= s1.w;
          }
          short tmp[8] = {f2b(u0.x),f2b(u0.y),f2b(u0.z),f2b(u0.w),
                          f2b(u1.x),f2b(u1.y),f2b(u1.z),f2b(u1.w)};
          __builtin_memcpy(&raw, tmp, 16);
        }
      }
      *(uint4*)&As[row*RP + cq*8] = raw;
    }
    {
      const int row = tid >> 2, cq = tid & 3;
      const int gc = c0 + cq*8, go = o_blk + row;
      uint4 raw = make_uint4(0,0,0,0);
      if (go < N && gc < K)
        raw = *(const uint4*)(Bz + (long long)go*K + gc);
      *(uint4*)&Bs[row*RP + cq*8] = raw;
    }
    __syncthreads();
    bf16x8 af[4], bfr[2];
    #pragma unroll
    for (int ts = 0; ts < 4; ++ts)
      af[ts] = *(const bf16x8*)&As[(w_s*64 + ts*16 + l15)*RP + l4*8];
    #pragma unroll
    for (int to = 0; to < 2; ++to)
      bfr[to] = *(const bf16x8*)&Bs[(w_o*32 + to*16 + l15)*RP + l4*8];
    #pragma unroll
    for (int to = 0; to < 2; ++to)
      #pragma unroll
      for (int ts = 0; ts < 4; ++ts)
        acc[to][ts] = __builtin_amdgcn_mfma_f32_16x16x32_bf16(af[ts], bfr[to], acc[to][ts], 0, 0, 0);
  }

  const int s_base = s_blk + w_s*64;
  const int o_base = o_blk + w_o*32;
  float* ozF = (float*)outp + (long long)z*oZ;
  short* ozH = (short*)outp + (long long)z*oZ;
  #pragma unroll
  for (int to = 0; to < 2; ++to) {
    const int o = o_base + to*16 + l15;
    const bool ov = (o < N);
    const float bv = (bias && ov) ? bias[o] : 0.f;
    float ps = 0.f, pq = 0.f;
    #pragma unroll
    for (int ts = 0; ts < 4; ++ts) {
      #pragma unroll
      for (int r = 0; r < 4; ++r) {
        const int s = s_base + ts*16 + l4*4 + r;
        float v = acc[to][ts][r] + bv;
        if (rowScale) v *= rowScale[(long long)z*rsZ + s];
        if (ov) {
          if (outBf16) ozH[(long long)s*ldo + o] = f2b(v);
          else         ozF[(long long)s*ldo + o] = v;
          ps += v; pq = fmaf(v, v, pq);
        }
      }
    }
    if (outPart) {
      ps += __shfl_down(ps, 32); pq += __shfl_down(pq, 32);
      ps += __shfl_down(ps, 16); pq += __shfl_down(pq, 16);
      if (lane < 16) {
        atomicAdd(&rowS[w_o*32 + to*16 + l15], ps);
        atomicAdd(&rowQ[w_o*32 + to*16 + l15], pq);
      }
    }
  }
  if (outPart) {
    __syncthreads();
    if (tid < 64) {
      const int o = o_blk + tid;
      if (o < N) {
        const int gl = o/grpCh - o_blk/grpCh;
        atomicAdd(&gSs[gl], rowS[tid]);
        atomicAdd(&gQs[gl], rowQ[tid]);
      }
    }
    __syncthreads();
    const int g0 = o_blk/grpCh;
    const int hi = (o_blk + 63 < N - 1) ? o_blk + 63 : N - 1;
    if (tid <= hi/grpCh - g0) {
      float* pp = outPart + (long long)z*pZ;
      atomicAdd(&pp[2*(g0+tid)],   gSs[tid]);
      atomicAdd(&pp[2*(g0+tid)+1], gQs[tid]);
    }
  }
}

// ---------- fused QK^T + softmax v2 ----------
// grid (NPTS/16, z), block 256 (4 waves). 16 query rows per block; each wave
// owns a 512-key strip. qkt is [z][n][64] bf16 (cols 48..63 zero). Pass 0:
// per-wave online (max,sum); LDS-combine across waves. Pass 1: recompute,
// write exp(s-M)/S transposed into attb[m][n] + per-key column-sum atomics.
__global__ __launch_bounds__(256) void attn_fused(
    const short* __restrict__ qkt,
    short* __restrict__ attb,
    float* __restrict__ colsum)
{
  const int tid = threadIdx.x;
  const int z = blockIdx.y;
  const int n0 = blockIdx.x * 16;
  const int w = tid >> 6, lane = tid & 63;
  const int l15 = lane & 15, l4 = lane >> 4;
  const short* qz = qkt + (long long)z*NPTS*64;
  short* az = attb + (long long)z*NPTS*NPTS;

  const bf16x8 aq0 = *(const bf16x8*)&qz[(n0+l15)*64 + l4*8];
  const bf16x8 aq1 = *(const bf16x8*)&qz[(n0+l15)*64 + 32 + l4*8];

  const int key0 = w * 512;
  float rmax[4], rsum[4], rinv[4];
  #pragma unroll
  for (int r = 0; r < 4; ++r) { rmax[r] = -1e30f; rsum[r] = 0.f; }

  #pragma unroll 1
  for (int t = 0; t < 8; ++t) {
    f32x4 acc[4];
    #pragma unroll
    for (int to = 0; to < 4; ++to) {
      const int k = key0 + t*64 + to*16 + l15;
      const bf16x8 b0 = *(const bf16x8*)&qz[k*64 + l4*8];
      const bf16x8 b1 = *(const bf16x8*)&qz[k*64 + 32 + l4*8];
      f32x4 a = (f32x4){0.f,0.f,0.f,0.f};
      a = __builtin_amdgcn_mfma_f32_16x16x32_bf16(aq0, b0, a, 0, 0, 0);
      a = __builtin_amdgcn_mfma_f32_16x16x32_bf16(aq1, b1, a, 0, 0, 0);
      acc[to] = a;
    }
    #pragma unroll
    for (int r = 0; r < 4; ++r) {
      float tmax = fmaxf(fmaxf(acc[0][r], acc[1][r]), fmaxf(acc[2][r], acc[3][r]));
      tmax = fmaxf(tmax, __shfl_xor(tmax, 1));
      tmax = fmaxf(tmax, __shfl_xor(tmax, 2));
      tmax = fmaxf(tmax, __shfl_xor(tmax, 4));
      tmax = fmaxf(tmax, __shfl_xor(tmax, 8));
      const float mnew = fmaxf(rmax[r], tmax);
      float p = __expf(acc[0][r]-mnew) + __expf(acc[1][r]-mnew)
              + __expf(acc[2][r]-mnew) + __expf(acc[3][r]-mnew);
      p += __shfl_xor(p, 1); p += __shfl_xor(p, 2);
      p += __shfl_xor(p, 4); p += __shfl_xor(p, 8);
      rsum[r] = rsum[r]*__expf(rmax[r]-mnew) + p;
      rmax[r] = mnew;
    }
  }

  __shared__ float sM[4][16], sS[4][16];
  if (l15 == 0) {
    #pragma unroll
    for (int r = 0; r < 4; ++r) { sM[w][l4*4+r] = rmax[r]; sS[w][l4*4+r] = rsum[r]; }
  }
  __syncthreads();
  #pragma unroll
  for (int r = 0; r < 4; ++r) {
    const int row = l4*4 + r;
    const float M = fmaxf(fmaxf(sM[0][row], sM[1][row]), fmaxf(sM[2][row], sM[3][row]));
    const float S = sS[0][row]*__expf(sM[0][row]-M) + sS[1][row]*__expf(sM[1][row]-M)
                  + sS[2][row]*__expf(sM[2][row]-M) + sS[3][row]*__expf(sM[3][row]-M);
    rmax[r] = M;
    rinv[r] = 1.0f / S;
  }

  #pragma unroll 1
  for (int t = 0; t < 8; ++t) {
    #pragma unroll
    for (int to = 0; to < 4; ++to) {
      const int k = key0 + t*64 + to*16 + l15;
      const bf16x8 b0 = *(const bf16x8*)&qz[k*64 + l4*8];
      const bf16x8 b1 = *(const bf16x8*)&qz[k*64 + 32 + l4*8];
      f32x4 a = (f32x4){0.f,0.f,0.f,0.f};
      a = __builtin_amdgcn_mfma_f32_16x16x32_bf16(aq0, b0, a, 0, 0, 0);
      a = __builtin_amdgcn_mfma_f32_16x16x32_bf16(aq1, b1, a, 0, 0, 0);
      short v4[4]; float cs = 0.f;
      #pragma unroll
      for (int r = 0; r < 4; ++r) {
        const float v = __expf(a[r] - rmax[r]) * rinv[r];
        v4[r] = f2b(v); cs += v;
      }
      uint2 raw; __builtin_memcpy(&raw, v4, 8);
      *(uint2*)&az[(long long)k*NPTS + n0 + l4*4] = raw;
      cs += __shfl_xor(cs, 16);
      cs += __shfl_xor(cs, 32);
      if (l4 == 0) atomicAdd(&colsum[(long long)z*NPTS + k], cs);
    }
  }
}

// ---------- finalize GN stats ----------
__global__ void fin_stats(float* __restrict__ part, float* __restrict__ stats,
                          long long slotStride, int G, float invGS)
{
  const int g = threadIdx.x;
  float* p  = part  + (long long)blockIdx.x * slotStride;
  float* st = stats + (long long)blockIdx.x * slotStride;
  if (g < G) {
    const float mu  = p[2*g] * invGS;
    const float var = p[2*g+1] * invGS - mu*mu;
    st[2*g]   = mu;
    st[2*g+1] = rsqrtf(var + 1e-5f);
    p[2*g] = 0.f; p[2*g+1] = 0.f;
  }
}

// ---------- maxpool accumulate ----------
__global__ __launch_bounds__(192) void maxpool_racc(const short* __restrict__ c3t, int kc,
                                                    long long c3Z, float* __restrict__ pool)
{
  const int n = blockIdx.x, z = blockIdx.y, c = threadIdx.x;
  const short* b = c3t + (long long)z*c3Z;
  float m = -1e30f;
  for (int r = 0; r < kc; ++r)
    m = fmaxf(m, b2f(b[((long long)r*NPTS + n)*192 + c]));
  float* p = &pool[((long long)z*NPTS + n)*192 + c];
  *p = fmaxf(*p, m);
}

// ---------- gn+relu on POOLt [4][NPTS][192] ----------
__global__ __launch_bounds__(256) void gn_pool(float* __restrict__ pool,
    const float* __restrict__ stats, const float* __restrict__ w, const float* __restrict__ b)
{
  const int i = blockIdx.x*256 + threadIdx.x;
  const int z = i / (NPTS*192);
  const int c = i % 192;
  const int g = c >> 5;
  const float* st = stats + z*64;
  const float v = (pool[i] - st[2*g]) * st[2*g+1] * w[c] + b[c];
  pool[i] = fmaxf(v, 0.f);
}

// ---------- FEATS slot[n][c] = xin[n][c] + relu(gn(t[n][c])) ----------
__global__ __launch_bounds__(256) void gn_resid(const float* __restrict__ t,
    const float* __restrict__ xin, long long xZ, long long xld,
    const float* __restrict__ stats,
    const float* __restrict__ w, const float* __restrict__ b,
    float* __restrict__ outp, long long oZ)
{
  const int i = blockIdx.x*256 + threadIdx.x;
  const int z = blockIdx.y;
  const int n = i / 192, c = i % 192, g = c >> 5;
  const float* st = stats + z*16;
  const float v = (t[(long long)z*NPTS*192 + i] - st[2*g]) * st[2*g+1] * w[c] + b[c];
  outp[(long long)z*oZ + (long long)n*768 + c] =
      xin[(long long)z*xZ + (long long)n*xld + c] + fmaxf(v, 0.f);
}

// ---------- transpose -> bf16: src[z][R][C] -> dst[z][C][R] ----------
template<int SRCF32>
__global__ __launch_bounds__(256) void tr2bf(const void* __restrict__ src, short* __restrict__ dst,
                                             long long sZ, long long dZ, int R, int C)
{
  __shared__ float t[32][33];
  const int z = blockIdx.z;
  const int c0 = blockIdx.x*32, r0 = blockIdx.y*32;
  const int tx = threadIdx.x % 32, ty = threadIdx.x / 32;
  #pragma unroll
  for (int j = 0; j < 4; ++j) {
    const int r = r0 + ty + j*8;
    const long long idx = (long long)z*sZ + (long long)r*C + c0 + tx;
    t[ty + j*8][tx] = SRCF32 ? ((const float*)src)[idx] : b2f(((const short*)src)[idx]);
  }
  __syncthreads();
  #pragma unroll
  for (int j = 0; j < 4; ++j) {
    const int c = c0 + ty + j*8;
    dst[(long long)z*dZ + (long long)c*R + r0 + tx] = f2b(t[tx][ty + j*8]);
  }
}

// 1/(1e-9+s) -> o; zero s for next use
__global__ __launch_bounds__(256) void recip_zero(float* __restrict__ s, float* __restrict__ o, int n)
{ const int i = blockIdx.x*256 + threadIdx.x; if (i < n) { o[i] = 1.0f/(1e-9f + s[i]); s[i] = 0.f; } }

// ---------- fuse epilogue: GN(16x48) + leaky(0.2) + L2 norm ----------
__global__ __launch_bounds__(256) void finalize_gn(const float* __restrict__ fused,
    const float* __restrict__ stats, const float* __restrict__ w, const float* __restrict__ b,
    float* __restrict__ outp, long long oZ)
{
  const int n = blockIdx.x, z = blockIdx.y, tid = threadIdx.x;
  const float* fz = fused + ((long long)z*NPTS + n)*768;
  const float* st = stats + z*32;
  __shared__ float vbuf[768];
  __shared__ float red[256];
  float ss = 0.f;
  for (int c = tid; c < 768; c += 256) {
    float v = fz[c];
    const int g = c / 48;
    v = (v - st[2*g]) * st[2*g+1] * w[c] + b[c];
    v = v > 0.f ? v : 0.2f * v;
    vbuf[c] = v;
    ss = fmaf(v, v, ss);
  }
  red[tid] = ss; __syncthreads();
  for (int st_ = 128; st_; st_ >>= 1) { if (tid < st_) red[tid] += red[tid+st_]; __syncthreads(); }
  const float inv = 1.0f / (sqrtf(red[0]) + 1e-8f);
  float* ob = outp + (long long)z*oZ + (long long)n*768;
  for (int c = tid; c < 768; c += 256) ob[c] = vbuf[c] * inv;
}

extern "C" void kernel_launch(void* const* d_in, const int* in_sizes, int n_in,
                              void* d_out, int out_size, void* d_ws, size_t ws_size,
                              hipStream_t stream)
{
  const float* src = (const float*)d_in[0];
  const float* tgt = (const float*)d_in[1];
  const float* lfw[3]  = {(const float*)d_in[5], (const float*)d_in[8],  (const float*)d_in[11]};
  const float* lfgw[3] = {(const float*)d_in[6], (const float*)d_in[9],  (const float*)d_in[12]};
  const float* lfgb[3] = {(const float*)d_in[7], (const float*)d_in[10], (const float*)d_in[13]};
  const float* qk_w = (const float*)d_in[14];
  const float* v_w  = (const float*)d_in[15];
  const float* v_b  = (const float*)d_in[16];
  const float* t_w  = (const float*)d_in[17];
  const float* t_b  = (const float*)d_in[18];
  const float* bgw  = (const float*)d_in[19];
  const float* bgb  = (const float*)d_in[20];
  const float* fw   = (const float*)d_in[21];
  const float* fgw  = (const float*)d_in[22];
  const float* fgb  = (const float*)d_in[23];
  float* dout = (float*)d_out;

  const size_t availFl = ws_size / sizeof(float);
  float* ws = (float*)d_ws;
  size_t off = 0;
  float* POOLt = ws + off; off += (size_t)4*NPTS*192;     // [4][n][192]
  float* PART  = ws + off; off += 1024;
  float* STATS = ws + off; off += 1024;
  float* SB    = ws + off; off += (size_t)4*NPTS;
  float* SINV  = ws + off; off += (size_t)4*NPTS;
  // bf16 weights (qkwb padded to 64 rows/head, rows 48..63 zero)
  short* wreg = (short*)(ws + off);
  short* lfw0b = wreg;              // 128x8
  short* lfw1b = lfw0b + 1024;      // 256x128
  short* lfw2b = lfw1b + 32768;     // 192x256
  short* qkwb  = lfw2b + 49152;     // 4x64x192 (padded)
  short* vwb   = qkwb + 49152;      // 4x192x192
  short* twb   = vwb + 147456;      // 4x192x192
  short* fwb   = twb + 147456;      // 768x768
  off += (1024+32768+49152+49152+147456+147456+589824 + 1)/2 + 8;
  short* FEATb = (short*)(ws + off); off += (size_t)4*SPC*8/2;  // [4][k*NPTS+m][8]
  off = (off + 63) & ~(size_t)63;
  float* REG = ws + off;
  const size_t regAvail = (availFl > off) ? (availFl - off) : 0;

  // attention batching: XRt+Tt+FUSED + (QKT[.][64]+Vt+Vc)/2 + ATTB/2 per z
  const size_t perZ = 4915200;
  int nz;
  if      (regAvail >= 4*perZ) nz = 4;
  else if (regAvail >= 2*perZ) nz = 2;
  else if (regAvail >= perZ)   nz = 1;
  else return;
  // conv chunking (z=4 batched): floats = 2,359,296 * kc
  int kc = 0;
  for (int cand = 64; cand >= 1; cand >>= 1)
    if ((size_t)2359296*cand <= regAvail) { kc = cand; break; }
  if (!kc) return;
  const int Sc = kc * NPTS;
  const int nChunks = KNB / kc;

  // conv view of REG
  short* C1t = (short*)REG;                         // [4][Sc][128]
  short* C2t = C1t + (size_t)4*Sc*128;              // [4][Sc][256]
  short* C3t = C2t + (size_t)4*Sc*256;              // [4][Sc][192]
  // attn view of REG
  float* XRt   = REG;                               // [nz][n][192]
  float* Tt    = XRt + (size_t)nz*NPTS*192;         // [nz][n][192]
  float* FUSED = Tt  + (size_t)nz*NPTS*192;         // [nz][n][768]
  short* QKT   = (short*)(FUSED + (size_t)nz*NPTS*768);  // [nz][n][64]
  short* Vt    = QKT + (size_t)nz*NPTS*64;          // [nz][n][192]
  short* Vc    = Vt  + (size_t)nz*NPTS*192;         // [nz][192][n]
  short* ATTB  = Vc  + (size_t)nz*NPTS*192;         // [nz][m][n]

  dim3 b256(256);
  const float invConv = 1.0f / (32.0f * (float)SPC);

  cvt_w<<<dim3(4),   b256, 0, stream>>>(lfw[0], lfw0b, 128, 6, 8);
  cvt_w<<<dim3(128), b256, 0, stream>>>(lfw[1], lfw1b, 256, 128, 128);
  cvt_w<<<dim3(192), b256, 0, stream>>>(lfw[2], lfw2b, 192, 256, 256);
  fill0<<<dim3(96), b256, 0, stream>>>((float*)qkwb, 24576);   // zero the padded qk weights
  for (int i = 0; i < 4; ++i)
    cvt_w<<<dim3(36), b256, 0, stream>>>(qk_w + (size_t)i*48*192, qkwb + (size_t)i*64*192, 48, 192, 192);
  cvt_w<<<dim3(576), b256, 0, stream>>>(v_w,  vwb,  768, 192, 192);
  cvt_w<<<dim3(576), b256, 0, stream>>>(t_w,  twb,  768, 192, 192);
  cvt_w<<<dim3(2304),b256, 0, stream>>>(fw,   fwb,  768, 768, 768);
  fill0<<<dim3(4), b256, 0, stream>>>(PART, 1024);
  fill0<<<dim3(32), b256, 0, stream>>>(SB, 4*NPTS);

  // ---- ball query ----
  bq_feat<<<dim3(NPTS/4, 4), b256, 0, stream>>>(src, tgt, FEATb);

  // ---- conv stage, z=4 batched, chunked with recompute if needed ----
  for (int ck = 0; ck < nChunks; ++ck)
    mm<1><<<dim3(Sc/128, 2, 4), b256, 0, stream>>>(
        FEATb + (size_t)ck*Sc*8, 8, (long long)SPC*8, nullptr,0,0,
        lfw0b, 0, C1t, 128, (long long)Sc*128, 1,
        nullptr, nullptr,0, nullptr,0,nullptr,nullptr,
        PART, 64, 32, 128, 8, Sc);
  fin_stats<<<4, 32, 0, stream>>>(PART, STATS, 64, 4, invConv);
  for (int ck = 0; ck < nChunks; ++ck) {
    if (nChunks > 1)
      mm<1><<<dim3(Sc/128, 2, 4), b256, 0, stream>>>(
          FEATb + (size_t)ck*Sc*8, 8, (long long)SPC*8, nullptr,0,0,
          lfw0b, 0, C1t, 128, (long long)Sc*128, 1,
          nullptr, nullptr,0, nullptr,0,nullptr,nullptr,
          nullptr, 0, 1, 128, 8, Sc);
    mm<1><<<dim3(Sc/128, 4, 4), b256, 0, stream>>>(
        C1t, 128, (long long)Sc*128, nullptr,0,0,
        lfw1b, 0, C2t, 256, (long long)Sc*256, 1,
        nullptr, nullptr,0, STATS,64, lfgw[0], lfgb[0],
        PART+256, 64, 32, 256, 128, Sc);
  }
  fin_stats<<<4, 32, 0, stream>>>(PART+256, STATS+256, 64, 8, invConv);
  fillv<<<dim3(4*NPTS*192/256), b256, 0, stream>>>(POOLt, 4*NPTS*192, -1e30f);
  for (int ck = 0; ck < nChunks; ++ck) {
    if (nChunks > 1) {
      mm<1><<<dim3(Sc/128, 2, 4), b256, 0, stream>>>(
          FEATb + (size_t)ck*Sc*8, 8, (long long)SPC*8, nullptr,0,0,
          lfw0b, 0, C1t, 128, (long long)Sc*128, 1,
          nullptr, nullptr,0, nullptr,0,nullptr,nullptr,
          nullptr, 0, 1, 128, 8, Sc);
      mm<1><<<dim3(Sc/128, 4, 4), b256, 0, stream>>>(
          C1t, 128, (long long)Sc*128, nullptr,0,0,
          lfw1b, 0, C2t, 256, (long long)Sc*256, 1,
          nullptr, nullptr,0, STATS,64, lfgw[0], lfgb[0],
          nullptr, 0, 1, 256, 128, Sc);
    }
    mm<1><<<dim3(Sc/128, 3, 4), b256, 0, stream>>>(
        C2t, 256, (long long)Sc*256, nullptr,0,0,
        lfw2b, 0, C3t, 192, (long long)Sc*192, 1,
        nullptr, nullptr,0, STATS+256,64, lfgw[1], lfgb[1],
        PART+512, 64, 32, 192, 256, Sc);
    maxpool_racc<<<dim3(NPTS, 4), dim3(192), 0, stream>>>(C3t, kc, (long long)Sc*192, POOLt);
  }
  fin_stats<<<4, 32, 0, stream>>>(PART+512, STATS+512, 64, 6, invConv);
  gn_pool<<<dim3(4*NPTS*192/256), b256, 0, stream>>>(POOLt, STATS+512, lfgw[2], lfgb[2]);

  // ---- attention + fuse, nz clouds per batch ----
  for (int bb0 = 0; bb0 < 4; bb0 += nz) {
    for (int i = 0; i < 4; ++i) {
      const float* Xin; long long xZ, xld;
      if (i == 0) { Xin = POOLt + (size_t)bb0*NPTS*192; xZ = (long long)NPTS*192; xld = 192; }
      else        { Xin = dout + (size_t)bb0*NPTS*768 + (size_t)(i-1)*192; xZ = (long long)NPTS*768; xld = 768; }
      // qk -> QKT [n][64] bf16 (cols 48..63 zero via padded weights)
      mm<0><<<dim3(16, 1, nz), b256, 0, stream>>>(
          Xin, xld, xZ, nullptr,0,0,
          qkwb + (size_t)i*64*192, 0, QKT, 64, (long long)NPTS*64, 1,
          nullptr, nullptr,0, nullptr,0,nullptr,nullptr,
          nullptr, 0, 1, 64, 192, NPTS);
      // v -> Vt [n][192] bf16 (+bias)
      mm<0><<<dim3(16, 3, nz), b256, 0, stream>>>(
          Xin, xld, xZ, nullptr,0,0,
          vwb + (size_t)i*192*192, 0, Vt, 192, (long long)NPTS*192, 1,
          v_b + (size_t)i*192, nullptr,0, nullptr,0,nullptr,nullptr,
          nullptr, 0, 1, 192, 192, NPTS);
      // fused QK^T + softmax -> ATTB bf16 [m][n] + column sums into SB
      attn_fused<<<dim3(NPTS/16, nz), b256, 0, stream>>>(QKT, ATTB, SB);
      recip_zero<<<dim3(nz*NPTS/256), b256, 0, stream>>>(SB, SINV, nz*NPTS);
      tr2bf<0><<<dim3(6, 64, nz), b256, 0, stream>>>(Vt, Vc,
          (long long)NPTS*192, (long long)192*NPTS, NPTS, 192);
      // x_r^T [m][192] = (ATTB . Vc^T) * sinv[m]
      mm<1><<<dim3(16, 3, nz), b256, 0, stream>>>(
          ATTB, NPTS, (long long)NPTS*NPTS, nullptr,0,0,
          Vc, (long long)192*NPTS, XRt, 192, (long long)NPTS*192, 0,
          nullptr, SINV, NPTS, nullptr,0,nullptr,nullptr,
          nullptr, 0, 1, 192, NPTS, NPTS);
      // t [n][192] = (x - x_r) . t_w^T + t_b, + stats
      mm<0><<<dim3(16, 3, nz), b256, 0, stream>>>(
          Xin, xld, xZ, XRt, 192, (long long)NPTS*192,
          twb + (size_t)i*192*192, 0, Tt, 192, (long long)NPTS*192, 0,
          t_b + (size_t)i*192, nullptr,0, nullptr,0,nullptr,nullptr,
          PART+768, 16, 32, 192, 192, NPTS);
      fin_stats<<<nz, 32, 0, stream>>>(PART+768, STATS+768, 16, 6, 1.0f/65536.0f);
      gn_resid<<<dim3(NPTS*192/256, nz), b256, 0, stream>>>(
          Tt, Xin, xZ, xld, STATS+768,
          bgw + (size_t)i*192, bgb + (size_t)i*192,
          dout + (size_t)bb0*NPTS*768 + (size_t)i*192, (long long)NPTS*768);
    }
    // fuse
    mm<0><<<dim3(16, 12, nz), b256, 0, stream>>>(
        dout + (size_t)bb0*NPTS*768, 768, (long long)NPTS*768, nullptr,0,0,
        fwb, 0, FUSED, 768, (long long)NPTS*768, 0,
        nullptr, nullptr,0, nullptr,0,nullptr,nullptr,
        PART+832, 32, 48, 768, 768, NPTS);
    fin_stats<<<nz, 32, 0, stream>>>(PART+832, STATS+832, 32, 16, 1.0f/98304.0f);
    finalize_gn<<<dim3(NPTS, nz), b256, 0, stream>>>(
        FUSED, STATS+832, fgw, fgb,
        dout + (size_t)bb0*NPTS*768, (long long)NPTS*768);
  }
}

// Round 7
// 1615.827 us; speedup vs baseline: 1.3957x; 1.1764x over previous
//
#include <hip/hip_runtime.h>
#include <hip/hip_bf16.h>
#include <math.h>

#define NPTS 2048
#define KNB 64
#define SPC (KNB*NPTS)

typedef short bf16x8 __attribute__((ext_vector_type(8)));
typedef float f32x4 __attribute__((ext_vector_type(4)));

static __device__ inline short f2b(float f){ __hip_bfloat16 h = __float2bfloat16(f); short s; __builtin_memcpy(&s,&h,2); return s; }
static __device__ inline float b2f(short s){ __hip_bfloat16 h; __builtin_memcpy(&h,&s,2); return __bfloat162float(h); }

// ---------- weight convert fp32[O][Cs] -> bf16[O][Cd] (zero pad c>=Cs) ----------
__global__ __launch_bounds__(256) void cvt_w(const float* __restrict__ src, short* __restrict__ dst,
                                             int O, int Cs, int Cd)
{
  const int i = blockIdx.x*256 + threadIdx.x;
  if (i >= O*Cd) return;
  const int o = i / Cd, c = i % Cd;
  dst[i] = (c < Cs) ? f2b(src[o*Cs + c]) : (short)0;
}

__global__ __launch_bounds__(256) void fill0(float* __restrict__ p, int n)
{ const int i = blockIdx.x*256 + threadIdx.x; if (i < n) p[i] = 0.f; }

__global__ __launch_bounds__(256) void fillv(float* __restrict__ p, int n, float v)
{ const int i = blockIdx.x*256 + threadIdx.x; if (i < n) p[i] = v; }

// ---------- ball query, wave-parallel; FEATb[z][k*NPTS+m][8] bf16 ----------
__global__ __launch_bounds__(256) void bq_feat(const float* __restrict__ src,
                                               const float* __restrict__ tgt,
                                               short* __restrict__ featb)
{
  const int z = blockIdx.y;
  const float* xyz = (z < 2) ? src + (size_t)z*NPTS*3 : tgt + (size_t)(z-2)*NPTS*3;
  __shared__ float cs[NPTS*3];
  for (int i = threadIdx.x; i < NPTS*3; i += 256) cs[i] = xyz[i];
  __syncthreads();
  const int wave = threadIdx.x >> 6, lane = threadIdx.x & 63;
  const int m = blockIdx.x*4 + wave;
  short* fb = featb + (long long)z*SPC*8;
  const float px = cs[3*m], py = cs[3*m+1], pz = cs[3*m+2];
  const float sqm = __fadd_rn(__fadd_rn(__fmul_rn(px,px), __fmul_rn(py,py)), __fmul_rn(pz,pz));
  const short pxh = f2b(px), pyh = f2b(py), pzh = f2b(pz);
  int cnt = 0;
  float frx = 0.f, fry = 0.f, frz = 0.f;
  for (int r = 0; r < 32; ++r) {
    const int n = r*64 + lane;
    const float xn = cs[3*n], yn = cs[3*n+1], zn = cs[3*n+2];
    const float sqn = __fadd_rn(__fadd_rn(__fmul_rn(xn,xn), __fmul_rn(yn,yn)), __fmul_rn(zn,zn));
    const float dt  = __fadd_rn(__fadd_rn(__fmul_rn(px,xn), __fmul_rn(py,yn)), __fmul_rn(pz,zn));
    const float d   = __fsub_rn(__fadd_rn(sqm, sqn), __fmul_rn(2.0f, dt));
    const bool hit = (d <= 0.09f);
    const unsigned long long mask = __ballot(hit);
    const int pre = __popcll(mask & ((1ull << lane) - 1ull));
    const int slot = cnt + pre;
    const float rx = xn-px, ry = yn-py, rz = zn-pz;
    if (hit && slot < KNB) {
      short tmp[8] = {pxh, pyh, pzh, f2b(rx), f2b(ry), f2b(rz), 0, 0};
      uint4 raw; __builtin_memcpy(&raw, tmp, 16);
      *(uint4*)&fb[((long long)slot*NPTS + m)*8] = raw;
    }
    if (cnt == 0 && mask) {
      const int fl = __ffsll(mask) - 1;
      frx = __shfl(rx, fl); fry = __shfl(ry, fl); frz = __shfl(rz, fl);
    }
    cnt += __popcll(mask);
    if (cnt >= KNB) break;
  }
  if (cnt < KNB && lane < KNB - cnt) {
    const int slot = cnt + lane;
    short tmp[8] = {pxh, pyh, pzh, f2b(frx), f2b(fry), f2b(frz), 0, 0};
    uint4 raw; __builtin_memcpy(&raw, tmp, 16);
    *(uint4*)&fb[((long long)slot*NPTS + m)*8] = raw;
  }
}

// ---------- fused conv1(+gn1+relu) -> conv2 ----------
// STAGE 0: conv1 raw stats only (grid y=1). STAGE 1: conv2 raw stats only.
// STAGE 2: store conv2 raw bf16 chunk. Block: 128 spatial x 64 conv2-out.
// Weights read directly from L2 (w1 [128][32] padded, w2 [256][128]).
template<int STAGE>
__global__ __launch_bounds__(256) void conv12(
    const short* __restrict__ featb, long long featZ,
    const short* __restrict__ w1, const short* __restrict__ w2,
    short* __restrict__ c2out, long long c2Z,
    const float* __restrict__ stats1,
    const float* __restrict__ g1w, const float* __restrict__ g1b,
    float* __restrict__ outPart, long long pZ)
{
  __shared__ __align__(16) short featA[128*40];
  __shared__ __align__(16) short As[128*136];
  __shared__ float gS[8], gQ[8];
  __shared__ float rowS[64], rowQ[64];
  const int tid = threadIdx.x;
  const int z = blockIdx.z;
  const int s_blk = blockIdx.x * 128;
  const int o_blk = blockIdx.y * 64;
  const int lane = tid & 63, widx = tid >> 6;
  const int w_s = widx & 1, w_h = widx >> 1;
  const int l15 = lane & 15, l4 = lane >> 4;

  if (tid < 8)  { gS[tid] = 0.f; gQ[tid] = 0.f; }
  if (STAGE == 1 && tid < 64) { rowS[tid] = 0.f; rowQ[tid] = 0.f; }

  // stage feat rows (8 real halves + zero pad to 32)
  if (tid < 128) {
    const int r = tid;
    const uint4 v = *(const uint4*)&featb[(long long)z*featZ + (long long)(s_blk + r)*8];
    const uint4 zz = make_uint4(0,0,0,0);
    *(uint4*)&featA[r*40]      = v;
    *(uint4*)&featA[r*40 + 8]  = zz;
    *(uint4*)&featA[r*40 + 16] = zz;
    *(uint4*)&featA[r*40 + 24] = zz;
  }
  __syncthreads();

  // conv1: wave computes 64s (w_s) x 64c (w_h), K=8 (padded to 32)
  f32x4 c1[4][4];
  {
    bf16x8 bw[4];
    #pragma unroll
    for (int tc = 0; tc < 4; ++tc)
      bw[tc] = *(const bf16x8*)&w1[(w_h*64 + tc*16 + l15)*32 + l4*8];
    #pragma unroll
    for (int ts = 0; ts < 4; ++ts) {
      const bf16x8 a = *(const bf16x8*)&featA[(w_s*64 + ts*16 + l15)*40 + l4*8];
      #pragma unroll
      for (int tc = 0; tc < 4; ++tc)
        c1[ts][tc] = __builtin_amdgcn_mfma_f32_16x16x32_bf16(a, bw[tc], (f32x4){0.f,0.f,0.f,0.f}, 0, 0, 0);
    }
  }

  if (STAGE == 0) {
    float ps0=0.f, pq0=0.f, ps1=0.f, pq1=0.f;
    #pragma unroll
    for (int ts = 0; ts < 4; ++ts)
      #pragma unroll
      for (int tc = 0; tc < 4; ++tc)
        #pragma unroll
        for (int r = 0; r < 4; ++r) {
          const float v = c1[ts][tc][r];
          if (tc < 2) { ps0 += v; pq0 = fmaf(v, v, pq0); }
          else        { ps1 += v; pq1 = fmaf(v, v, pq1); }
        }
    #pragma unroll
    for (int d = 32; d; d >>= 1) {
      ps0 += __shfl_down(ps0, d); pq0 += __shfl_down(pq0, d);
      ps1 += __shfl_down(ps1, d); pq1 += __shfl_down(pq1, d);
    }
    if (lane == 0) {
      atomicAdd(&gS[w_h*2],   ps0); atomicAdd(&gQ[w_h*2],   pq0);
      atomicAdd(&gS[w_h*2+1], ps1); atomicAdd(&gQ[w_h*2+1], pq1);
    }
    __syncthreads();
    if (tid < 4) {
      atomicAdd(&outPart[(long long)z*pZ + 2*tid],     gS[tid]);
      atomicAdd(&outPart[(long long)z*pZ + 2*tid + 1], gQ[tid]);
    }
    return;
  }

  // gn1 + relu -> As bf16 [128][128]
  {
    const float* st1 = stats1 + (long long)z*64;
    #pragma unroll
    for (int tc = 0; tc < 4; ++tc) {
      const int c = w_h*64 + tc*16 + l15;
      const int g = c >> 5;
      const float mu = st1[2*g], rs = st1[2*g+1];
      const float wv = g1w[c], bv = g1b[c];
      #pragma unroll
      for (int ts = 0; ts < 4; ++ts)
        #pragma unroll
        for (int r = 0; r < 4; ++r) {
          const int s = w_s*64 + ts*16 + l4*4 + r;
          As[s*136 + c] = f2b(fmaxf((c1[ts][tc][r] - mu)*rs*wv + bv, 0.f));
        }
    }
  }
  __syncthreads();

  // conv2: wave 64s (w_s) x 32o (w_h of the 64-o slab), K=128
  f32x4 acc[2][4];
  #pragma unroll
  for (int i = 0; i < 2; ++i)
    #pragma unroll
    for (int j = 0; j < 4; ++j) acc[i][j] = (f32x4){0.f,0.f,0.f,0.f};
  #pragma unroll
  for (int c0 = 0; c0 < 128; c0 += 32) {
    bf16x8 af[4], bfr[2];
    #pragma unroll
    for (int ts = 0; ts < 4; ++ts)
      af[ts] = *(const bf16x8*)&As[(w_s*64 + ts*16 + l15)*136 + c0 + l4*8];
    #pragma unroll
    for (int to = 0; to < 2; ++to)
      bfr[to] = *(const bf16x8*)&w2[(o_blk + w_h*32 + to*16 + l15)*128 + c0 + l4*8];
    #pragma unroll
    for (int to = 0; to < 2; ++to)
      #pragma unroll
      for (int ts = 0; ts < 4; ++ts)
        acc[to][ts] = __builtin_amdgcn_mfma_f32_16x16x32_bf16(af[ts], bfr[to], acc[to][ts], 0, 0, 0);
  }

  short* oz = (STAGE == 2) ? c2out + (long long)z*c2Z : nullptr;
  #pragma unroll
  for (int to = 0; to < 2; ++to) {
    const int o = o_blk + w_h*32 + to*16 + l15;
    float ps = 0.f, pq = 0.f;
    #pragma unroll
    for (int ts = 0; ts < 4; ++ts)
      #pragma unroll
      for (int r = 0; r < 4; ++r) {
        const int s = s_blk + w_s*64 + ts*16 + l4*4 + r;
        const float v = acc[to][ts][r];
        if (STAGE == 2) oz[(long long)s*256 + o] = f2b(v);
        ps += v; pq = fmaf(v, v, pq);
      }
    if (STAGE == 1) {
      ps += __shfl_down(ps, 32); pq += __shfl_down(pq, 32);
      ps += __shfl_down(ps, 16); pq += __shfl_down(pq, 16);
      if (lane < 16) {
        atomicAdd(&rowS[w_h*32 + to*16 + l15], ps);
        atomicAdd(&rowQ[w_h*32 + to*16 + l15], pq);
      }
    }
  }
  if (STAGE == 1) {
    __syncthreads();
    if (tid < 64) {
      atomicAdd(&gS[tid >> 5], rowS[tid]);
      atomicAdd(&gQ[tid >> 5], rowQ[tid]);
    }
    __syncthreads();
    if (tid < 2) {
      const int g0 = o_blk >> 5;
      atomicAdd(&outPart[(long long)z*pZ + 2*(g0+tid)],     gS[tid]);
      atomicAdd(&outPart[(long long)z*pZ + 2*(g0+tid) + 1], gQ[tid]);
    }
  }
}

// ---------- universal MFMA GEMM (tile 128s x 64o) ----------
template<int ABF16>
__global__ __launch_bounds__(256) void mm(
    const void* __restrict__ Ap, long long ldA, long long aZ,
    const float* __restrict__ A2, long long ldA2, long long a2Z,
    const short* __restrict__ Bw, long long bZ,
    void* __restrict__ outp, long long ldo, long long oZ, int outBf16,
    const float* __restrict__ bias,
    const float* __restrict__ rowScale, long long rsZ,
    const float* __restrict__ inStats, long long isZ,
    const float* __restrict__ inW, const float* __restrict__ inB,
    float* __restrict__ outPart, long long pZ, int grpCh,
    int N, int K, int S)
{
  constexpr int RP = 40;
  __shared__ __align__(16) short As[128*RP];
  __shared__ __align__(16) short Bs[64*RP];
  __shared__ float rowS[64], rowQ[64], gSs[4], gQs[4];
  const int tid = threadIdx.x;
  const int z = blockIdx.z;
  const int s_blk = blockIdx.x*128;
  const int o_blk = blockIdx.y*64;
  const int lane = tid & 63;
  const int widx = tid >> 6;
  const int w_s = widx & 1, w_o = widx >> 1;
  const int l15 = lane & 15, l4 = lane >> 4;

  const short* Bz = Bw + (long long)z*bZ;
  const float* stz = inStats ? inStats + (long long)z*isZ : nullptr;

  f32x4 acc[2][4];
  #pragma unroll
  for (int i = 0; i < 2; ++i)
    #pragma unroll
    for (int j = 0; j < 4; ++j) acc[i][j] = (f32x4){0.f,0.f,0.f,0.f};

  if (outPart) {
    if (tid < 64) { rowS[tid] = 0.f; rowQ[tid] = 0.f; }
    if (tid < 4)  { gSs[tid] = 0.f; gQs[tid] = 0.f; }
  }

  for (int c0 = 0; c0 < K; c0 += 32) {
    __syncthreads();
    #pragma unroll
    for (int it = 0; it < 2; ++it) {
      const int ch = tid + it*256;
      const int row = ch >> 2, cq = ch & 3;
      const int gc = c0 + cq*8;
      uint4 raw = make_uint4(0,0,0,0);
      if (gc < K) {
        const long long base = (long long)(s_blk+row)*ldA + gc;
        if (ABF16) {
          raw = *(const uint4*)((const short*)Ap + (long long)z*aZ + base);
          if (stz) {
            short vs[8]; __builtin_memcpy(vs, &raw, 16);
            const int g = gc >> 5;
            const float mu = stz[2*g], rsg = stz[2*g+1];
            short tmp[8];
            #pragma unroll
            for (int j = 0; j < 8; ++j) {
              const float v = (b2f(vs[j]) - mu)*rsg*inW[gc+j] + inB[gc+j];
              tmp[j] = f2b(fmaxf(v, 0.f));
            }
            __builtin_memcpy(&raw, tmp, 16);
          }
        } else {
          const float* Af = (const float*)Ap + (long long)z*aZ + base;
          float4 u0 = *(const float4*)Af;
          float4 u1 = *(const float4*)(Af + 4);
          if (A2) {
            const float* Sf = A2 + (long long)z*a2Z + (long long)(s_blk+row)*ldA2 + gc;
            const float4 s0 = *(const float4*)Sf, s1 = *(const float4*)(Sf + 4);
            u0.x -= s0.x; u0.y -= s0.y; u0.z -= s0.z; u0.w -= s0.w;
            u1.x -= s1.x; u1.y -= s1.y; u1.z -= s1.z; u1.w -= s1.w;
          }
          short tmp[8] = {f2b(u0.x),f2b(u0.y),f2b(u0.z),f2b(u0.w),
                          f2b(u1.x),f2b(u1.y),f2b(u1.z),f2b(u1.w)};
          __builtin_memcpy(&raw, tmp, 16);
        }
      }
      *(uint4*)&As[row*RP + cq*8] = raw;
    }
    {
      const int row = tid >> 2, cq = tid & 3;
      const int gc = c0 + cq*8, go = o_blk + row;
      uint4 raw = make_uint4(0,0,0,0);
      if (go < N && gc < K)
        raw = *(const uint4*)(Bz + (long long)go*K + gc);
      *(uint4*)&Bs[row*RP + cq*8] = raw;
    }
    __syncthreads();
    bf16x8 af[4], bfr[2];
    #pragma unroll
    for (int ts = 0; ts < 4; ++ts)
      af[ts] = *(const bf16x8*)&As[(w_s*64 + ts*16 + l15)*RP + l4*8];
    #pragma unroll
    for (int to = 0; to < 2; ++to)
      bfr[to] = *(const bf16x8*)&Bs[(w_o*32 + to*16 + l15)*RP + l4*8];
    #pragma unroll
    for (int to = 0; to < 2; ++to)
      #pragma unroll
      for (int ts = 0; ts < 4; ++ts)
        acc[to][ts] = __builtin_amdgcn_mfma_f32_16x16x32_bf16(af[ts], bfr[to], acc[to][ts], 0, 0, 0);
  }

  const int s_base = s_blk + w_s*64;
  const int o_base = o_blk + w_o*32;
  float* ozF = (float*)outp + (long long)z*oZ;
  short* ozH = (short*)outp + (long long)z*oZ;
  #pragma unroll
  for (int to = 0; to < 2; ++to) {
    const int o = o_base + to*16 + l15;
    const bool ov = (o < N);
    const float bv = (bias && ov) ? bias[o] : 0.f;
    float ps = 0.f, pq = 0.f;
    #pragma unroll
    for (int ts = 0; ts < 4; ++ts) {
      #pragma unroll
      for (int r = 0; r < 4; ++r) {
        const int s = s_base + ts*16 + l4*4 + r;
        float v = acc[to][ts][r] + bv;
        if (rowScale) v *= rowScale[(long long)z*rsZ + s];
        if (ov) {
          if (outBf16) ozH[(long long)s*ldo + o] = f2b(v);
          else         ozF[(long long)s*ldo + o] = v;
          ps += v; pq = fmaf(v, v, pq);
        }
      }
    }
    if (outPart) {
      ps += __shfl_down(ps, 32); pq += __shfl_down(pq, 32);
      ps += __shfl_down(ps, 16); pq += __shfl_down(pq, 16);
      if (lane < 16) {
        atomicAdd(&rowS[w_o*32 + to*16 + l15], ps);
        atomicAdd(&rowQ[w_o*32 + to*16 + l15], pq);
      }
    }
  }
  if (outPart) {
    __syncthreads();
    if (tid < 64) {
      const int o = o_blk + tid;
      if (o < N) {
        const int gl = o/grpCh - o_blk/grpCh;
        atomicAdd(&gSs[gl], rowS[tid]);
        atomicAdd(&gQs[gl], rowQ[tid]);
      }
    }
    __syncthreads();
    const int g0 = o_blk/grpCh;
    const int hi = (o_blk + 63 < N - 1) ? o_blk + 63 : N - 1;
    if (tid <= hi/grpCh - g0) {
      float* pp = outPart + (long long)z*pZ;
      atomicAdd(&pp[2*(g0+tid)],   gSs[tid]);
      atomicAdd(&pp[2*(g0+tid)+1], gQs[tid]);
    }
  }
}

// ---------- fused QK^T + softmax v2 ----------
__global__ __launch_bounds__(256) void attn_fused(
    const short* __restrict__ qkt,
    short* __restrict__ attb,
    float* __restrict__ colsum)
{
  const int tid = threadIdx.x;
  const int z = blockIdx.y;
  const int n0 = blockIdx.x * 16;
  const int w = tid >> 6, lane = tid & 63;
  const int l15 = lane & 15, l4 = lane >> 4;
  const short* qz = qkt + (long long)z*NPTS*64;
  short* az = attb + (long long)z*NPTS*NPTS;

  const bf16x8 aq0 = *(const bf16x8*)&qz[(n0+l15)*64 + l4*8];
  const bf16x8 aq1 = *(const bf16x8*)&qz[(n0+l15)*64 + 32 + l4*8];

  const int key0 = w * 512;
  float rmax[4], rsum[4], rinv[4];
  #pragma unroll
  for (int r = 0; r < 4; ++r) { rmax[r] = -1e30f; rsum[r] = 0.f; }

  #pragma unroll 1
  for (int t = 0; t < 8; ++t) {
    f32x4 acc[4];
    #pragma unroll
    for (int to = 0; to < 4; ++to) {
      const int k = key0 + t*64 + to*16 + l15;
      const bf16x8 b0 = *(const bf16x8*)&qz[k*64 + l4*8];
      const bf16x8 b1 = *(const bf16x8*)&qz[k*64 + 32 + l4*8];
      f32x4 a = (f32x4){0.f,0.f,0.f,0.f};
      a = __builtin_amdgcn_mfma_f32_16x16x32_bf16(aq0, b0, a, 0, 0, 0);
      a = __builtin_amdgcn_mfma_f32_16x16x32_bf16(aq1, b1, a, 0, 0, 0);
      acc[to] = a;
    }
    #pragma unroll
    for (int r = 0; r < 4; ++r) {
      float tmax = fmaxf(fmaxf(acc[0][r], acc[1][r]), fmaxf(acc[2][r], acc[3][r]));
      tmax = fmaxf(tmax, __shfl_xor(tmax, 1));
      tmax = fmaxf(tmax, __shfl_xor(tmax, 2));
      tmax = fmaxf(tmax, __shfl_xor(tmax, 4));
      tmax = fmaxf(tmax, __shfl_xor(tmax, 8));
      const float mnew = fmaxf(rmax[r], tmax);
      float p = __expf(acc[0][r]-mnew) + __expf(acc[1][r]-mnew)
              + __expf(acc[2][r]-mnew) + __expf(acc[3][r]-mnew);
      p += __shfl_xor(p, 1); p += __shfl_xor(p, 2);
      p += __shfl_xor(p, 4); p += __shfl_xor(p, 8);
      rsum[r] = rsum[r]*__expf(rmax[r]-mnew) + p;
      rmax[r] = mnew;
    }
  }

  __shared__ float sM[4][16], sS[4][16];
  if (l15 == 0) {
    #pragma unroll
    for (int r = 0; r < 4; ++r) { sM[w][l4*4+r] = rmax[r]; sS[w][l4*4+r] = rsum[r]; }
  }
  __syncthreads();
  #pragma unroll
  for (int r = 0; r < 4; ++r) {
    const int row = l4*4 + r;
    const float M = fmaxf(fmaxf(sM[0][row], sM[1][row]), fmaxf(sM[2][row], sM[3][row]));
    const float S = sS[0][row]*__expf(sM[0][row]-M) + sS[1][row]*__expf(sM[1][row]-M)
                  + sS[2][row]*__expf(sM[2][row]-M) + sS[3][row]*__expf(sM[3][row]-M);
    rmax[r] = M;
    rinv[r] = 1.0f / S;
  }

  #pragma unroll 1
  for (int t = 0; t < 8; ++t) {
    #pragma unroll
    for (int to = 0; to < 4; ++to) {
      const int k = key0 + t*64 + to*16 + l15;
      const bf16x8 b0 = *(const bf16x8*)&qz[k*64 + l4*8];
      const bf16x8 b1 = *(const bf16x8*)&qz[k*64 + 32 + l4*8];
      f32x4 a = (f32x4){0.f,0.f,0.f,0.f};
      a = __builtin_amdgcn_mfma_f32_16x16x32_bf16(aq0, b0, a, 0, 0, 0);
      a = __builtin_amdgcn_mfma_f32_16x16x32_bf16(aq1, b1, a, 0, 0, 0);
      short v4[4]; float cs = 0.f;
      #pragma unroll
      for (int r = 0; r < 4; ++r) {
        const float v = __expf(a[r] - rmax[r]) * rinv[r];
        v4[r] = f2b(v); cs += v;
      }
      uint2 raw; __builtin_memcpy(&raw, v4, 8);
      *(uint2*)&az[(long long)k*NPTS + n0 + l4*4] = raw;
      cs += __shfl_xor(cs, 16);
      cs += __shfl_xor(cs, 32);
      if (l4 == 0) atomicAdd(&colsum[(long long)z*NPTS + k], cs);
    }
  }
}

// ---------- finalize GN stats ----------
__global__ void fin_stats(float* __restrict__ part, float* __restrict__ stats,
                          long long slotStride, int G, float invGS)
{
  const int g = threadIdx.x;
  float* p  = part  + (long long)blockIdx.x * slotStride;
  float* st = stats + (long long)blockIdx.x * slotStride;
  if (g < G) {
    const float mu  = p[2*g] * invGS;
    const float var = p[2*g+1] * invGS - mu*mu;
    st[2*g]   = mu;
    st[2*g+1] = rsqrtf(var + 1e-5f);
    p[2*g] = 0.f; p[2*g+1] = 0.f;
  }
}

// ---------- maxpool accumulate ----------
__global__ __launch_bounds__(192) void maxpool_racc(const short* __restrict__ c3t, int kc,
                                                    long long c3Z, float* __restrict__ pool)
{
  const int n = blockIdx.x, z = blockIdx.y, c = threadIdx.x;
  const short* b = c3t + (long long)z*c3Z;
  float m = -1e30f;
  for (int r = 0; r < kc; ++r)
    m = fmaxf(m, b2f(b[((long long)r*NPTS + n)*192 + c]));
  float* p = &pool[((long long)z*NPTS + n)*192 + c];
  *p = fmaxf(*p, m);
}

// ---------- gn+relu on POOLt [4][NPTS][192] ----------
__global__ __launch_bounds__(256) void gn_pool(float* __restrict__ pool,
    const float* __restrict__ stats, const float* __restrict__ w, const float* __restrict__ b)
{
  const int i = blockIdx.x*256 + threadIdx.x;
  const int z = i / (NPTS*192);
  const int c = i % 192;
  const int g = c >> 5;
  const float* st = stats + z*64;
  const float v = (pool[i] - st[2*g]) * st[2*g+1] * w[c] + b[c];
  pool[i] = fmaxf(v, 0.f);
}

// ---------- FEATS slot[n][c] = xin[n][c] + relu(gn(t[n][c])) ----------
__global__ __launch_bounds__(256) void gn_resid(const float* __restrict__ t,
    const float* __restrict__ xin, long long xZ, long long xld,
    const float* __restrict__ stats,
    const float* __restrict__ w, const float* __restrict__ b,
    float* __restrict__ outp, long long oZ)
{
  const int i = blockIdx.x*256 + threadIdx.x;
  const int z = blockIdx.y;
  const int n = i / 192, c = i % 192, g = c >> 5;
  const float* st = stats + z*16;
  const float v = (t[(long long)z*NPTS*192 + i] - st[2*g]) * st[2*g+1] * w[c] + b[c];
  outp[(long long)z*oZ + (long long)n*768 + c] =
      xin[(long long)z*xZ + (long long)n*xld + c] + fmaxf(v, 0.f);
}

// ---------- transpose -> bf16: src[z][R][C] -> dst[z][C][R] ----------
template<int SRCF32>
__global__ __launch_bounds__(256) void tr2bf(const void* __restrict__ src, short* __restrict__ dst,
                                             long long sZ, long long dZ, int R, int C)
{
  __shared__ float t[32][33];
  const int z = blockIdx.z;
  const int c0 = blockIdx.x*32, r0 = blockIdx.y*32;
  const int tx = threadIdx.x % 32, ty = threadIdx.x / 32;
  #pragma unroll
  for (int j = 0; j < 4; ++j) {
    const int r = r0 + ty + j*8;
    const long long idx = (long long)z*sZ + (long long)r*C + c0 + tx;
    t[ty + j*8][tx] = SRCF32 ? ((const float*)src)[idx] : b2f(((const short*)src)[idx]);
  }
  __syncthreads();
  #pragma unroll
  for (int j = 0; j < 4; ++j) {
    const int c = c0 + ty + j*8;
    dst[(long long)z*dZ + (long long)c*R + r0 + tx] = f2b(t[tx][ty + j*8]);
  }
}

// 1/(1e-9+s) -> o; zero s for next use
__global__ __launch_bounds__(256) void recip_zero(float* __restrict__ s, float* __restrict__ o, int n)
{ const int i = blockIdx.x*256 + threadIdx.x; if (i < n) { o[i] = 1.0f/(1e-9f + s[i]); s[i] = 0.f; } }

// ---------- fuse epilogue: GN(16x48) + leaky(0.2) + L2 norm ----------
__global__ __launch_bounds__(256) void finalize_gn(const float* __restrict__ fused,
    const float* __restrict__ stats, const float* __restrict__ w, const float* __restrict__ b,
    float* __restrict__ outp, long long oZ)
{
  const int n = blockIdx.x, z = blockIdx.y, tid = threadIdx.x;
  const float* fz = fused + ((long long)z*NPTS + n)*768;
  const float* st = stats + z*32;
  __shared__ float vbuf[768];
  __shared__ float red[256];
  float ss = 0.f;
  for (int c = tid; c < 768; c += 256) {
    float v = fz[c];
    const int g = c / 48;
    v = (v - st[2*g]) * st[2*g+1] * w[c] + b[c];
    v = v > 0.f ? v : 0.2f * v;
    vbuf[c] = v;
    ss = fmaf(v, v, ss);
  }
  red[tid] = ss; __syncthreads();
  for (int st_ = 128; st_; st_ >>= 1) { if (tid < st_) red[tid] += red[tid+st_]; __syncthreads(); }
  const float inv = 1.0f / (sqrtf(red[0]) + 1e-8f);
  float* ob = outp + (long long)z*oZ + (long long)n*768;
  for (int c = tid; c < 768; c += 256) ob[c] = vbuf[c] * inv;
}

extern "C" void kernel_launch(void* const* d_in, const int* in_sizes, int n_in,
                              void* d_out, int out_size, void* d_ws, size_t ws_size,
                              hipStream_t stream)
{
  const float* src = (const float*)d_in[0];
  const float* tgt = (const float*)d_in[1];
  const float* lfw[3]  = {(const float*)d_in[5], (const float*)d_in[8],  (const float*)d_in[11]};
  const float* lfgw[3] = {(const float*)d_in[6], (const float*)d_in[9],  (const float*)d_in[12]};
  const float* lfgb[3] = {(const float*)d_in[7], (const float*)d_in[10], (const float*)d_in[13]};
  const float* qk_w = (const float*)d_in[14];
  const float* v_w  = (const float*)d_in[15];
  const float* v_b  = (const float*)d_in[16];
  const float* t_w  = (const float*)d_in[17];
  const float* t_b  = (const float*)d_in[18];
  const float* bgw  = (const float*)d_in[19];
  const float* bgb  = (const float*)d_in[20];
  const float* fw   = (const float*)d_in[21];
  const float* fgw  = (const float*)d_in[22];
  const float* fgb  = (const float*)d_in[23];
  float* dout = (float*)d_out;

  const size_t availFl = ws_size / sizeof(float);
  float* ws = (float*)d_ws;
  size_t off = 0;
  float* POOLt = ws + off; off += (size_t)4*NPTS*192;     // [4][n][192]
  float* PART  = ws + off; off += 1024;
  float* STATS = ws + off; off += 1024;
  float* SB    = ws + off; off += (size_t)4*NPTS;
  float* SINV  = ws + off; off += (size_t)4*NPTS;
  // bf16 weights (lfw0b padded to K=32; qkwb padded to 64 rows/head)
  short* wreg = (short*)(ws + off);
  short* lfw0b = wreg;              // 128x32
  short* lfw1b = lfw0b + 4096;      // 256x128
  short* lfw2b = lfw1b + 32768;     // 192x256
  short* qkwb  = lfw2b + 49152;     // 4x64x192 (padded)
  short* vwb   = qkwb + 49152;      // 4x192x192
  short* twb   = vwb + 147456;      // 4x192x192
  short* fwb   = twb + 147456;      // 768x768
  off += (4096+32768+49152+49152+147456+147456+589824 + 1)/2 + 8;
  short* FEATb = (short*)(ws + off); off += (size_t)4*SPC*8/2;  // [4][k*NPTS+m][8]
  off = (off + 63) & ~(size_t)63;
  float* REG = ws + off;
  const size_t regAvail = (availFl > off) ? (availFl - off) : 0;

  // attention batching: XRt+Tt+FUSED + (QKT[.][64]+Vt+Vc)/2 + ATTB/2 per z
  const size_t perZ = 4915200;
  int nz;
  if      (regAvail >= 4*perZ) nz = 4;
  else if (regAvail >= 2*perZ) nz = 2;
  else if (regAvail >= perZ)   nz = 1;
  else return;
  // conv chunking (z=4 batched): floats per kc-row-block = 2*2048*(256+192) = 1,835,008
  int kc = 0;
  for (int cand = 64; cand >= 1; cand >>= 1)
    if ((size_t)1835008*cand <= regAvail) { kc = cand; break; }
  if (!kc) return;
  const int Sc = kc * NPTS;
  const int nChunks = KNB / kc;

  // conv view of REG (C1 never materialized)
  short* C2t = (short*)REG;                         // [4][Sc][256]
  short* C3t = C2t + (size_t)4*Sc*256;              // [4][Sc][192]
  // attn view of REG
  float* XRt   = REG;                               // [nz][n][192]
  float* Tt    = XRt + (size_t)nz*NPTS*192;         // [nz][n][192]
  float* FUSED = Tt  + (size_t)nz*NPTS*192;         // [nz][n][768]
  short* QKT   = (short*)(FUSED + (size_t)nz*NPTS*768);  // [nz][n][64]
  short* Vt    = QKT + (size_t)nz*NPTS*64;          // [nz][n][192]
  short* Vc    = Vt  + (size_t)nz*NPTS*192;         // [nz][192][n]
  short* ATTB  = Vc  + (size_t)nz*NPTS*192;         // [nz][m][n]

  dim3 b256(256);
  const float invConv = 1.0f / (32.0f * (float)SPC);

  cvt_w<<<dim3(16),  b256, 0, stream>>>(lfw[0], lfw0b, 128, 6, 32);
  cvt_w<<<dim3(128), b256, 0, stream>>>(lfw[1], lfw1b, 256, 128, 128);
  cvt_w<<<dim3(192), b256, 0, stream>>>(lfw[2], lfw2b, 192, 256, 256);
  fill0<<<dim3(96), b256, 0, stream>>>((float*)qkwb, 24576);   // zero the padded qk weights
  for (int i = 0; i < 4; ++i)
    cvt_w<<<dim3(36), b256, 0, stream>>>(qk_w + (size_t)i*48*192, qkwb + (size_t)i*64*192, 48, 192, 192);
  cvt_w<<<dim3(576), b256, 0, stream>>>(v_w,  vwb,  768, 192, 192);
  cvt_w<<<dim3(576), b256, 0, stream>>>(t_w,  twb,  768, 192, 192);
  cvt_w<<<dim3(2304),b256, 0, stream>>>(fw,   fwb,  768, 768, 768);
  fill0<<<dim3(4), b256, 0, stream>>>(PART, 1024);
  fill0<<<dim3(32), b256, 0, stream>>>(SB, 4*NPTS);

  // ---- ball query ----
  bq_feat<<<dim3(NPTS/4, 4), b256, 0, stream>>>(src, tgt, FEATb);

  // ---- conv stage: fused conv1->conv2, 3 passes, chunked ----
  // pass 1: conv1 raw stats
  for (int ck = 0; ck < nChunks; ++ck)
    conv12<0><<<dim3(Sc/128, 1, 4), b256, 0, stream>>>(
        FEATb + (size_t)ck*Sc*8, (long long)SPC*8, lfw0b, nullptr,
        nullptr, 0, nullptr, nullptr, nullptr, PART, 64);
  fin_stats<<<4, 32, 0, stream>>>(PART, STATS, 64, 4, invConv);
  // pass 2: conv2 raw stats (no store)
  for (int ck = 0; ck < nChunks; ++ck)
    conv12<1><<<dim3(Sc/128, 4, 4), b256, 0, stream>>>(
        FEATb + (size_t)ck*Sc*8, (long long)SPC*8, lfw0b, lfw1b,
        nullptr, 0, STATS, lfgw[0], lfgb[0], PART+256, 64);
  fin_stats<<<4, 32, 0, stream>>>(PART+256, STATS+256, 64, 8, invConv);
  // pass 3: conv2 store chunk -> conv3 -> maxpool
  fillv<<<dim3(4*NPTS*192/256), b256, 0, stream>>>(POOLt, 4*NPTS*192, -1e30f);
  for (int ck = 0; ck < nChunks; ++ck) {
    conv12<2><<<dim3(Sc/128, 4, 4), b256, 0, stream>>>(
        FEATb + (size_t)ck*Sc*8, (long long)SPC*8, lfw0b, lfw1b,
        C2t, (long long)Sc*256, STATS, lfgw[0], lfgb[0], nullptr, 0);
    mm<1><<<dim3(Sc/128, 3, 4), b256, 0, stream>>>(
        C2t, 256, (long long)Sc*256, nullptr,0,0,
        lfw2b, 0, C3t, 192, (long long)Sc*192, 1,
        nullptr, nullptr,0, STATS+256,64, lfgw[1], lfgb[1],
        PART+512, 64, 32, 192, 256, Sc);
    maxpool_racc<<<dim3(NPTS, 4), dim3(192), 0, stream>>>(C3t, kc, (long long)Sc*192, POOLt);
  }
  fin_stats<<<4, 32, 0, stream>>>(PART+512, STATS+512, 64, 6, invConv);
  gn_pool<<<dim3(4*NPTS*192/256), b256, 0, stream>>>(POOLt, STATS+512, lfgw[2], lfgb[2]);

  // ---- attention + fuse, nz clouds per batch ----
  for (int bb0 = 0; bb0 < 4; bb0 += nz) {
    for (int i = 0; i < 4; ++i) {
      const float* Xin; long long xZ, xld;
      if (i == 0) { Xin = POOLt + (size_t)bb0*NPTS*192; xZ = (long long)NPTS*192; xld = 192; }
      else        { Xin = dout + (size_t)bb0*NPTS*768 + (size_t)(i-1)*192; xZ = (long long)NPTS*768; xld = 768; }
      // qk -> QKT [n][64] bf16 (cols 48..63 zero via padded weights)
      mm<0><<<dim3(16, 1, nz), b256, 0, stream>>>(
          Xin, xld, xZ, nullptr,0,0,
          qkwb + (size_t)i*64*192, 0, QKT, 64, (long long)NPTS*64, 1,
          nullptr, nullptr,0, nullptr,0,nullptr,nullptr,
          nullptr, 0, 1, 64, 192, NPTS);
      // v -> Vt [n][192] bf16 (+bias)
      mm<0><<<dim3(16, 3, nz), b256, 0, stream>>>(
          Xin, xld, xZ, nullptr,0,0,
          vwb + (size_t)i*192*192, 0, Vt, 192, (long long)NPTS*192, 1,
          v_b + (size_t)i*192, nullptr,0, nullptr,0,nullptr,nullptr,
          nullptr, 0, 1, 192, 192, NPTS);
      // fused QK^T + softmax -> ATTB bf16 [m][n] + column sums into SB
      attn_fused<<<dim3(NPTS/16, nz), b256, 0, stream>>>(QKT, ATTB, SB);
      recip_zero<<<dim3(nz*NPTS/256), b256, 0, stream>>>(SB, SINV, nz*NPTS);
      tr2bf<0><<<dim3(6, 64, nz), b256, 0, stream>>>(Vt, Vc,
          (long long)NPTS*192, (long long)192*NPTS, NPTS, 192);
      // x_r^T [m][192] = (ATTB . Vc^T) * sinv[m]
      mm<1><<<dim3(16, 3, nz), b256, 0, stream>>>(
          ATTB, NPTS, (long long)NPTS*NPTS, nullptr,0,0,
          Vc, (long long)192*NPTS, XRt, 192, (long long)NPTS*192, 0,
          nullptr, SINV, NPTS, nullptr,0,nullptr,nullptr,
          nullptr, 0, 1, 192, NPTS, NPTS);
      // t [n][192] = (x - x_r) . t_w^T + t_b, + stats
      mm<0><<<dim3(16, 3, nz), b256, 0, stream>>>(
          Xin, xld, xZ, XRt, 192, (long long)NPTS*192,
          twb + (size_t)i*192*192, 0, Tt, 192, (long long)NPTS*192, 0,
          t_b + (size_t)i*192, nullptr,0, nullptr,0,nullptr,nullptr,
          PART+768, 16, 32, 192, 192, NPTS);
      fin_stats<<<nz, 32, 0, stream>>>(PART+768, STATS+768, 16, 6, 1.0f/65536.0f);
      gn_resid<<<dim3(NPTS*192/256, nz), b256, 0, stream>>>(
          Tt, Xin, xZ, xld, STATS+768,
          bgw + (size_t)i*192, bgb + (size_t)i*192,
          dout + (size_t)bb0*NPTS*768 + (size_t)i*192, (long long)NPTS*768);
    }
    // fuse
    mm<0><<<dim3(16, 12, nz), b256, 0, stream>>>(
        dout + (size_t)bb0*NPTS*768, 768, (long long)NPTS*768, nullptr,0,0,
        fwb, 0, FUSED, 768, (long long)NPTS*768, 0,
        nullptr, nullptr,0, nullptr,0,nullptr,nullptr,
        PART+832, 32, 48, 768, 768, NPTS);
    fin_stats<<<nz, 32, 0, stream>>>(PART+832, STATS+832, 32, 16, 1.0f/98304.0f);
    finalize_gn<<<dim3(NPTS, nz), b256, 0, stream>>>(
        FUSED, STATS+832, fgw, fgb,
        dout + (size_t)bb0*NPTS*768, (long long)NPTS*768);
  }
}

// Round 8
// 1277.586 us; speedup vs baseline: 1.7652x; 1.2647x over previous
//
#include <hip/hip_runtime.h>
#include <hip/hip_bf16.h>
#include <math.h>

#define NPTS 2048
#define KNB 64
#define SPC (KNB*NPTS)

typedef short bf16x8 __attribute__((ext_vector_type(8)));
typedef float f32x4 __attribute__((ext_vector_type(4)));

static __device__ inline short f2b(float f){ __hip_bfloat16 h = __float2bfloat16(f); short s; __builtin_memcpy(&s,&h,2); return s; }
static __device__ inline float b2f(short s){ __hip_bfloat16 h; __builtin_memcpy(&h,&s,2); return __bfloat162float(h); }

// ---------- weight convert fp32[O][Cs] -> bf16[O][Cd] (zero pad c>=Cs) ----------
__global__ __launch_bounds__(256) void cvt_w(const float* __restrict__ src, short* __restrict__ dst,
                                             int O, int Cs, int Cd)
{
  const int i = blockIdx.x*256 + threadIdx.x;
  if (i >= O*Cd) return;
  const int o = i / Cd, c = i % Cd;
  dst[i] = (c < Cs) ? f2b(src[o*Cs + c]) : (short)0;
}

__global__ __launch_bounds__(256) void fill0(float* __restrict__ p, int n)
{ const int i = blockIdx.x*256 + threadIdx.x; if (i < n) p[i] = 0.f; }

// ---------- ball query, wave-parallel; FEATb[z][k*NPTS+m][8] bf16 ----------
__global__ __launch_bounds__(256) void bq_feat(const float* __restrict__ src,
                                               const float* __restrict__ tgt,
                                               short* __restrict__ featb)
{
  const int z = blockIdx.y;
  const float* xyz = (z < 2) ? src + (size_t)z*NPTS*3 : tgt + (size_t)(z-2)*NPTS*3;
  __shared__ float cs[NPTS*3];
  for (int i = threadIdx.x; i < NPTS*3; i += 256) cs[i] = xyz[i];
  __syncthreads();
  const int wave = threadIdx.x >> 6, lane = threadIdx.x & 63;
  const int m = blockIdx.x*4 + wave;
  short* fb = featb + (long long)z*SPC*8;
  const float px = cs[3*m], py = cs[3*m+1], pz = cs[3*m+2];
  const float sqm = __fadd_rn(__fadd_rn(__fmul_rn(px,px), __fmul_rn(py,py)), __fmul_rn(pz,pz));
  const short pxh = f2b(px), pyh = f2b(py), pzh = f2b(pz);
  int cnt = 0;
  float frx = 0.f, fry = 0.f, frz = 0.f;
  for (int r = 0; r < 32; ++r) {
    const int n = r*64 + lane;
    const float xn = cs[3*n], yn = cs[3*n+1], zn = cs[3*n+2];
    const float sqn = __fadd_rn(__fadd_rn(__fmul_rn(xn,xn), __fmul_rn(yn,yn)), __fmul_rn(zn,zn));
    const float dt  = __fadd_rn(__fadd_rn(__fmul_rn(px,xn), __fmul_rn(py,yn)), __fmul_rn(pz,zn));
    const float d   = __fsub_rn(__fadd_rn(sqm, sqn), __fmul_rn(2.0f, dt));
    const bool hit = (d <= 0.09f);
    const unsigned long long mask = __ballot(hit);
    const int pre = __popcll(mask & ((1ull << lane) - 1ull));
    const int slot = cnt + pre;
    const float rx = xn-px, ry = yn-py, rz = zn-pz;
    if (hit && slot < KNB) {
      short tmp[8] = {pxh, pyh, pzh, f2b(rx), f2b(ry), f2b(rz), 0, 0};
      uint4 raw; __builtin_memcpy(&raw, tmp, 16);
      *(uint4*)&fb[((long long)slot*NPTS + m)*8] = raw;
    }
    if (cnt == 0 && mask) {
      const int fl = __ffsll(mask) - 1;
      frx = __shfl(rx, fl); fry = __shfl(ry, fl); frz = __shfl(rz, fl);
    }
    cnt += __popcll(mask);
    if (cnt >= KNB) break;
  }
  if (cnt < KNB && lane < KNB - cnt) {
    const int slot = cnt + lane;
    short tmp[8] = {pxh, pyh, pzh, f2b(frx), f2b(fry), f2b(frz), 0, 0};
    uint4 raw; __builtin_memcpy(&raw, tmp, 16);
    *(uint4*)&fb[((long long)slot*NPTS + m)*8] = raw;
  }
}

// ---------- fully-fused conv tower: conv1->gn1->conv2->gn2->conv3->maxpool ----------
// Block owns 16 m-rows, loops all 64 k in chunks of 8 (tile = 128 rows).
// STAGE 0: conv1 raw stats. STAGE 1: conv2 raw stats. STAGE 2: conv3 raw stats
// + per-(m,c) max over k -> pool[z][m][192] (each entry written exactly once).
template<int STAGE>
__global__ __launch_bounds__(256) void convfused(
    const short* __restrict__ featb,
    const short* __restrict__ w1, const short* __restrict__ w2, const short* __restrict__ w3,
    const float* __restrict__ stats1, const float* __restrict__ g1w, const float* __restrict__ g1b,
    const float* __restrict__ stats2, const float* __restrict__ g2w, const float* __restrict__ g2b,
    float* __restrict__ pool,
    float* __restrict__ outPart, long long pZ)
{
  __shared__ __align__(16) char arena[79872];
  short* featA = (short*)arena;             // [128][40]
  short* As    = (short*)(arena + 10240);   // [128][136]
  short* C2s   = (short*)(arena + 45056);   // [128][136]
  const int tid = threadIdx.x;
  const int z = blockIdx.z;
  const int m0 = blockIdx.x * 16;
  const int lane = tid & 63, w = tid >> 6;
  const int w_s = w & 1, w_h = w >> 1;
  const int l15 = lane & 15, l4 = lane >> 4;
  const short* fz = featb + (long long)z*SPC*8;

  float s0[2] = {0.f,0.f}, q0[2] = {0.f,0.f};
  float s2[2][2] = {{0.f,0.f},{0.f,0.f}}, q2[2][2] = {{0.f,0.f},{0.f,0.f}};
  float s3[3] = {0.f,0.f,0.f}, q3[3] = {0.f,0.f,0.f};
  f32x4 mx[6];
  #pragma unroll
  for (int j = 0; j < 6; ++j) mx[j] = (f32x4){-1e30f,-1e30f,-1e30f,-1e30f};
  f32x4 c3[4][6];

  #pragma unroll 1
  for (int it = 0; it < 8; ++it) {
    const int k0 = it*8;
    __syncthreads();
    if (tid < 128) {
      const long long g = (long long)(k0 + (tid>>4))*NPTS + m0 + (tid&15);
      const uint4 v = *(const uint4*)&fz[g*8];
      const uint4 zz = make_uint4(0,0,0,0);
      *(uint4*)&featA[tid*40]      = v;
      *(uint4*)&featA[tid*40 + 8]  = zz;
      *(uint4*)&featA[tid*40 + 16] = zz;
      *(uint4*)&featA[tid*40 + 24] = zz;
    }
    __syncthreads();
    // conv1: wave = 64 rows (w_s) x 64 ch (w_h), K=8 padded to 32
    f32x4 c1[4][4];
    {
      bf16x8 bw[4];
      #pragma unroll
      for (int tc = 0; tc < 4; ++tc)
        bw[tc] = *(const bf16x8*)&w1[(w_h*64 + tc*16 + l15)*32 + l4*8];
      #pragma unroll
      for (int ts = 0; ts < 4; ++ts) {
        const bf16x8 a = *(const bf16x8*)&featA[(w_s*64 + ts*16 + l15)*40 + l4*8];
        #pragma unroll
        for (int tc = 0; tc < 4; ++tc)
          c1[ts][tc] = __builtin_amdgcn_mfma_f32_16x16x32_bf16(a, bw[tc], (f32x4){0.f,0.f,0.f,0.f}, 0, 0, 0);
      }
    }
    if (STAGE == 0) {
      #pragma unroll
      for (int ts = 0; ts < 4; ++ts)
        #pragma unroll
        for (int tc = 0; tc < 4; ++tc)
          #pragma unroll
          for (int r = 0; r < 4; ++r) {
            const float v = c1[ts][tc][r];
            s0[tc>>1] += v; q0[tc>>1] = fmaf(v, v, q0[tc>>1]);
          }
      continue;
    }
    // gn1+relu -> As [128][128]
    {
      const float* st1 = stats1 + (long long)z*64;
      #pragma unroll
      for (int tc = 0; tc < 4; ++tc) {
        const int c = w_h*64 + tc*16 + l15;
        const int g = c >> 5;
        const float mu = st1[2*g], rs = st1[2*g+1];
        const float wv = g1w[c], bv = g1b[c];
        #pragma unroll
        for (int ts = 0; ts < 4; ++ts)
          #pragma unroll
          for (int r = 0; r < 4; ++r)
            As[(w_s*64 + ts*16 + l4*4 + r)*136 + c] = f2b(fmaxf((c1[ts][tc][r] - mu)*rs*wv + bv, 0.f));
      }
    }
    __syncthreads();
    // conv2 in two 128-channel halves
    #pragma unroll
    for (int h = 0; h < 2; ++h) {
      f32x4 c2[4][4];
      #pragma unroll
      for (int i = 0; i < 4; ++i)
        #pragma unroll
        for (int j = 0; j < 4; ++j) c2[i][j] = (f32x4){0.f,0.f,0.f,0.f};
      const int ob = h*128 + w_h*64;
      #pragma unroll
      for (int c0 = 0; c0 < 128; c0 += 32) {
        bf16x8 af[4], bw[4];
        #pragma unroll
        for (int ts = 0; ts < 4; ++ts)
          af[ts] = *(const bf16x8*)&As[(w_s*64 + ts*16 + l15)*136 + c0 + l4*8];
        #pragma unroll
        for (int tc = 0; tc < 4; ++tc)
          bw[tc] = *(const bf16x8*)&w2[(ob + tc*16 + l15)*128 + c0 + l4*8];
        #pragma unroll
        for (int ts = 0; ts < 4; ++ts)
          #pragma unroll
          for (int tc = 0; tc < 4; ++tc)
            c2[ts][tc] = __builtin_amdgcn_mfma_f32_16x16x32_bf16(af[ts], bw[tc], c2[ts][tc], 0, 0, 0);
      }
      if (STAGE == 1) {
        #pragma unroll
        for (int ts = 0; ts < 4; ++ts)
          #pragma unroll
          for (int tc = 0; tc < 4; ++tc)
            #pragma unroll
            for (int r = 0; r < 4; ++r) {
              const float v = c2[ts][tc][r];
              s2[h][tc>>1] += v; q2[h][tc>>1] = fmaf(v, v, q2[h][tc>>1]);
            }
      } else {
        // gn2+relu -> C2s [128][128] (this half)
        const float* st2 = stats2 + (long long)z*64;
        #pragma unroll
        for (int tc = 0; tc < 4; ++tc) {
          const int c = ob + tc*16 + l15;
          const int g = c >> 5;
          const float mu = st2[2*g], rs = st2[2*g+1];
          const float wv = g2w[c], bv = g2b[c];
          const int cl = w_h*64 + tc*16 + l15;
          #pragma unroll
          for (int ts = 0; ts < 4; ++ts)
            #pragma unroll
            for (int r = 0; r < 4; ++r)
              C2s[(w_s*64 + ts*16 + l4*4 + r)*136 + cl] = f2b(fmaxf((c2[ts][tc][r] - mu)*rs*wv + bv, 0.f));
        }
        __syncthreads();
        // conv3 partial over this half's K=128
        if (h == 0) {
          #pragma unroll
          for (int i = 0; i < 4; ++i)
            #pragma unroll
            for (int j = 0; j < 6; ++j) c3[i][j] = (f32x4){0.f,0.f,0.f,0.f};
        }
        #pragma unroll
        for (int c0 = 0; c0 < 128; c0 += 32) {
          bf16x8 af[4];
          #pragma unroll
          for (int ts = 0; ts < 4; ++ts)
            af[ts] = *(const bf16x8*)&C2s[(w_s*64 + ts*16 + l15)*136 + c0 + l4*8];
          #pragma unroll
          for (int t6 = 0; t6 < 6; ++t6) {
            const bf16x8 bw6 = *(const bf16x8*)&w3[(w_h*96 + t6*16 + l15)*256 + h*128 + c0 + l4*8];
            #pragma unroll
            for (int ts = 0; ts < 4; ++ts)
              c3[ts][t6] = __builtin_amdgcn_mfma_f32_16x16x32_bf16(af[ts], bw6, c3[ts][t6], 0, 0, 0);
          }
        }
        __syncthreads();
      }
    }
    if (STAGE == 2) {
      #pragma unroll
      for (int t6 = 0; t6 < 6; ++t6)
        #pragma unroll
        for (int r = 0; r < 4; ++r) {
          const float v0 = c3[0][t6][r], v1 = c3[1][t6][r];
          const float v2 = c3[2][t6][r], v3 = c3[3][t6][r];
          s3[t6>>1] += (v0+v1) + (v2+v3);
          q3[t6>>1] = fmaf(v0,v0, fmaf(v1,v1, fmaf(v2,v2, fmaf(v3,v3, q3[t6>>1]))));
          mx[t6][r] = fmaxf(mx[t6][r], fmaxf(fmaxf(v0,v1), fmaxf(v2,v3)));
        }
    }
  }

  // ---- final reductions ----
  if (STAGE == 0) {
    #pragma unroll
    for (int j = 0; j < 2; ++j) {
      float s = s0[j], q = q0[j];
      #pragma unroll
      for (int d = 32; d; d >>= 1) { s += __shfl_down(s, d); q += __shfl_down(q, d); }
      if (lane == 0) {
        float* pp = outPart + (long long)z*pZ;
        atomicAdd(&pp[2*(w_h*2+j)], s); atomicAdd(&pp[2*(w_h*2+j)+1], q);
      }
    }
  } else if (STAGE == 1) {
    #pragma unroll
    for (int h = 0; h < 2; ++h)
      #pragma unroll
      for (int j = 0; j < 2; ++j) {
        float s = s2[h][j], q = q2[h][j];
        #pragma unroll
        for (int d = 32; d; d >>= 1) { s += __shfl_down(s, d); q += __shfl_down(q, d); }
        if (lane == 0) {
          const int g = h*4 + w_h*2 + j;
          float* pp = outPart + (long long)z*pZ;
          atomicAdd(&pp[2*g], s); atomicAdd(&pp[2*g+1], q);
        }
      }
  } else {
    #pragma unroll
    for (int j = 0; j < 3; ++j) {
      float s = s3[j], q = q3[j];
      #pragma unroll
      for (int d = 32; d; d >>= 1) { s += __shfl_down(s, d); q += __shfl_down(q, d); }
      if (lane == 0) {
        const int g = w_h*3 + j;
        float* pp = outPart + (long long)z*pZ;
        atomicAdd(&pp[2*g], s); atomicAdd(&pp[2*g+1], q);
      }
    }
    // combine max across the two w_s waves via LDS, store POOL
    float* pb = (float*)arena;   // [2][16][192]
    __syncthreads();
    #pragma unroll
    for (int t6 = 0; t6 < 6; ++t6)
      #pragma unroll
      for (int r = 0; r < 4; ++r)
        pb[(w_s*16 + l4*4 + r)*192 + w_h*96 + t6*16 + l15] = mx[t6][r];
    __syncthreads();
    for (int t = tid; t < 16*192; t += 256) {
      const int m = t / 192, c = t % 192;
      const float v = fmaxf(pb[m*192 + c], pb[(16+m)*192 + c]);
      pool[((long long)z*NPTS + m0 + m)*192 + c] = v;
    }
  }
}

// ---------- universal MFMA GEMM (tile 128s x 64o) ----------
template<int ABF16>
__global__ __launch_bounds__(256) void mm(
    const void* __restrict__ Ap, long long ldA, long long aZ,
    const float* __restrict__ A2, long long ldA2, long long a2Z,
    const short* __restrict__ Bw, long long bZ,
    void* __restrict__ outp, long long ldo, long long oZ, int outBf16,
    const float* __restrict__ bias,
    const float* __restrict__ rowScale, long long rsZ,
    const float* __restrict__ inStats, long long isZ,
    const float* __restrict__ inW, const float* __restrict__ inB,
    float* __restrict__ outPart, long long pZ, int grpCh,
    int N, int K, int S)
{
  constexpr int RP = 40;
  __shared__ __align__(16) short As[128*RP];
  __shared__ __align__(16) short Bs[64*RP];
  __shared__ float rowS[64], rowQ[64], gSs[4], gQs[4];
  const int tid = threadIdx.x;
  const int z = blockIdx.z;
  const int s_blk = blockIdx.x*128;
  const int o_blk = blockIdx.y*64;
  const int lane = tid & 63;
  const int widx = tid >> 6;
  const int w_s = widx & 1, w_o = widx >> 1;
  const int l15 = lane & 15, l4 = lane >> 4;

  const short* Bz = Bw + (long long)z*bZ;
  const float* stz = inStats ? inStats + (long long)z*isZ : nullptr;

  f32x4 acc[2][4];
  #pragma unroll
  for (int i = 0; i < 2; ++i)
    #pragma unroll
    for (int j = 0; j < 4; ++j) acc[i][j] = (f32x4){0.f,0.f,0.f,0.f};

  if (outPart) {
    if (tid < 64) { rowS[tid] = 0.f; rowQ[tid] = 0.f; }
    if (tid < 4)  { gSs[tid] = 0.f; gQs[tid] = 0.f; }
  }

  for (int c0 = 0; c0 < K; c0 += 32) {
    __syncthreads();
    #pragma unroll
    for (int it = 0; it < 2; ++it) {
      const int ch = tid + it*256;
      const int row = ch >> 2, cq = ch & 3;
      const int gc = c0 + cq*8;
      uint4 raw = make_uint4(0,0,0,0);
      if (gc < K) {
        const long long base = (long long)(s_blk+row)*ldA + gc;
        if (ABF16) {
          raw = *(const uint4*)((const short*)Ap + (long long)z*aZ + base);
          if (stz) {
            short vs[8]; __builtin_memcpy(vs, &raw, 16);
            const int g = gc >> 5;
            const float mu = stz[2*g], rsg = stz[2*g+1];
            short tmp[8];
            #pragma unroll
            for (int j = 0; j < 8; ++j) {
              const float v = (b2f(vs[j]) - mu)*rsg*inW[gc+j] + inB[gc+j];
              tmp[j] = f2b(fmaxf(v, 0.f));
            }
            __builtin_memcpy(&raw, tmp, 16);
          }
        } else {
          const float* Af = (const float*)Ap + (long long)z*aZ + base;
          float4 u0 = *(const float4*)Af;
          float4 u1 = *(const float4*)(Af + 4);
          if (A2) {
            const float* Sf = A2 + (long long)z*a2Z + (long long)(s_blk+row)*ldA2 + gc;
            const float4 s0 = *(const float4*)Sf, s1 = *(const float4*)(Sf + 4);
            u0.x -= s0.x; u0.y -= s0.y; u0.z -= s0.z; u0.w -= s0.w;
            u1.x -= s1.x; u1.y -= s1.y; u1.z -= s1.z; u1.w -= s1.w;
          }
          short tmp[8] = {f2b(u0.x),f2b(u0.y),f2b(u0.z),f2b(u0.w),
                          f2b(u1.x),f2b(u1.y),f2b(u1.z),f2b(u1.w)};
          __builtin_memcpy(&raw, tmp, 16);
        }
      }
      *(uint4*)&As[row*RP + cq*8] = raw;
    }
    {
      const int row = tid >> 2, cq = tid & 3;
      const int gc = c0 + cq*8, go = o_blk + row;
      uint4 raw = make_uint4(0,0,0,0);
      if (go < N && gc < K)
        raw = *(const uint4*)(Bz + (long long)go*K + gc);
      *(uint4*)&Bs[row*RP + cq*8] = raw;
    }
    __syncthreads();
    bf16x8 af[4], bfr[2];
    #pragma unroll
    for (int ts = 0; ts < 4; ++ts)
      af[ts] = *(const bf16x8*)&As[(w_s*64 + ts*16 + l15)*RP + l4*8];
    #pragma unroll
    for (int to = 0; to < 2; ++to)
      bfr[to] = *(const bf16x8*)&Bs[(w_o*32 + to*16 + l15)*RP + l4*8];
    #pragma unroll
    for (int to = 0; to < 2; ++to)
      #pragma unroll
      for (int ts = 0; ts < 4; ++ts)
        acc[to][ts] = __builtin_amdgcn_mfma_f32_16x16x32_bf16(af[ts], bfr[to], acc[to][ts], 0, 0, 0);
  }

  const int s_base = s_blk + w_s*64;
  const int o_base = o_blk + w_o*32;
  float* ozF = (float*)outp + (long long)z*oZ;
  short* ozH = (short*)outp + (long long)z*oZ;
  #pragma unroll
  for (int to = 0; to < 2; ++to) {
    const int o = o_base + to*16 + l15;
    const bool ov = (o < N);
    const float bv = (bias && ov) ? bias[o] : 0.f;
    float ps = 0.f, pq = 0.f;
    #pragma unroll
    for (int ts = 0; ts < 4; ++ts) {
      #pragma unroll
      for (int r = 0; r < 4; ++r) {
        const int s = s_base + ts*16 + l4*4 + r;
        float v = acc[to][ts][r] + bv;
        if (rowScale) v *= rowScale[(long long)z*rsZ + s];
        if (ov) {
          if (outBf16) ozH[(long long)s*ldo + o] = f2b(v);
          else         ozF[(long long)s*ldo + o] = v;
          ps += v; pq = fmaf(v, v, pq);
        }
      }
    }
    if (outPart) {
      ps += __shfl_down(ps, 32); pq += __shfl_down(pq, 32);
      ps += __shfl_down(ps, 16); pq += __shfl_down(pq, 16);
      if (lane < 16) {
        atomicAdd(&rowS[w_o*32 + to*16 + l15], ps);
        atomicAdd(&rowQ[w_o*32 + to*16 + l15], pq);
      }
    }
  }
  if (outPart) {
    __syncthreads();
    if (tid < 64) {
      const int o = o_blk + tid;
      if (o < N) {
        const int gl = o/grpCh - o_blk/grpCh;
        atomicAdd(&gSs[gl], rowS[tid]);
        atomicAdd(&gQs[gl], rowQ[tid]);
      }
    }
    __syncthreads();
    const int g0 = o_blk/grpCh;
    const int hi = (o_blk + 63 < N - 1) ? o_blk + 63 : N - 1;
    if (tid <= hi/grpCh - g0) {
      float* pp = outPart + (long long)z*pZ;
      atomicAdd(&pp[2*(g0+tid)],   gSs[tid]);
      atomicAdd(&pp[2*(g0+tid)+1], gQs[tid]);
    }
  }
}

// ---------- fused QK^T + softmax ----------
__global__ __launch_bounds__(256) void attn_fused(
    const short* __restrict__ qkt,
    short* __restrict__ attb,
    float* __restrict__ colsum)
{
  const int tid = threadIdx.x;
  const int z = blockIdx.y;
  const int n0 = blockIdx.x * 16;
  const int w = tid >> 6, lane = tid & 63;
  const int l15 = lane & 15, l4 = lane >> 4;
  const short* qz = qkt + (long long)z*NPTS*64;
  short* az = attb + (long long)z*NPTS*NPTS;

  const bf16x8 aq0 = *(const bf16x8*)&qz[(n0+l15)*64 + l4*8];
  const bf16x8 aq1 = *(const bf16x8*)&qz[(n0+l15)*64 + 32 + l4*8];

  const int key0 = w * 512;
  float rmax[4], rsum[4], rinv[4];
  #pragma unroll
  for (int r = 0; r < 4; ++r) { rmax[r] = -1e30f; rsum[r] = 0.f; }

  #pragma unroll 1
  for (int t = 0; t < 8; ++t) {
    f32x4 acc[4];
    #pragma unroll
    for (int to = 0; to < 4; ++to) {
      const int k = key0 + t*64 + to*16 + l15;
      const bf16x8 b0 = *(const bf16x8*)&qz[k*64 + l4*8];
      const bf16x8 b1 = *(const bf16x8*)&qz[k*64 + 32 + l4*8];
      f32x4 a = (f32x4){0.f,0.f,0.f,0.f};
      a = __builtin_amdgcn_mfma_f32_16x16x32_bf16(aq0, b0, a, 0, 0, 0);
      a = __builtin_amdgcn_mfma_f32_16x16x32_bf16(aq1, b1, a, 0, 0, 0);
      acc[to] = a;
    }
    #pragma unroll
    for (int r = 0; r < 4; ++r) {
      float tmax = fmaxf(fmaxf(acc[0][r], acc[1][r]), fmaxf(acc[2][r], acc[3][r]));
      tmax = fmaxf(tmax, __shfl_xor(tmax, 1));
      tmax = fmaxf(tmax, __shfl_xor(tmax, 2));
      tmax = fmaxf(tmax, __shfl_xor(tmax, 4));
      tmax = fmaxf(tmax, __shfl_xor(tmax, 8));
      const float mnew = fmaxf(rmax[r], tmax);
      float p = __expf(acc[0][r]-mnew) + __expf(acc[1][r]-mnew)
              + __expf(acc[2][r]-mnew) + __expf(acc[3][r]-mnew);
      p += __shfl_xor(p, 1); p += __shfl_xor(p, 2);
      p += __shfl_xor(p, 4); p += __shfl_xor(p, 8);
      rsum[r] = rsum[r]*__expf(rmax[r]-mnew) + p;
      rmax[r] = mnew;
    }
  }

  __shared__ float sM[4][16], sS[4][16];
  if (l15 == 0) {
    #pragma unroll
    for (int r = 0; r < 4; ++r) { sM[w][l4*4+r] = rmax[r]; sS[w][l4*4+r] = rsum[r]; }
  }
  __syncthreads();
  #pragma unroll
  for (int r = 0; r < 4; ++r) {
    const int row = l4*4 + r;
    const float M = fmaxf(fmaxf(sM[0][row], sM[1][row]), fmaxf(sM[2][row], sM[3][row]));
    const float S = sS[0][row]*__expf(sM[0][row]-M) + sS[1][row]*__expf(sM[1][row]-M)
                  + sS[2][row]*__expf(sM[2][row]-M) + sS[3][row]*__expf(sM[3][row]-M);
    rmax[r] = M;
    rinv[r] = 1.0f / S;
  }

  #pragma unroll 1
  for (int t = 0; t < 8; ++t) {
    #pragma unroll
    for (int to = 0; to < 4; ++to) {
      const int k = key0 + t*64 + to*16 + l15;
      const bf16x8 b0 = *(const bf16x8*)&qz[k*64 + l4*8];
      const bf16x8 b1 = *(const bf16x8*)&qz[k*64 + 32 + l4*8];
      f32x4 a = (f32x4){0.f,0.f,0.f,0.f};
      a = __builtin_amdgcn_mfma_f32_16x16x32_bf16(aq0, b0, a, 0, 0, 0);
      a = __builtin_amdgcn_mfma_f32_16x16x32_bf16(aq1, b1, a, 0, 0, 0);
      short v4[4]; float cs = 0.f;
      #pragma unroll
      for (int r = 0; r < 4; ++r) {
        const float v = __expf(a[r] - rmax[r]) * rinv[r];
        v4[r] = f2b(v); cs += v;
      }
      uint2 raw; __builtin_memcpy(&raw, v4, 8);
      *(uint2*)&az[(long long)k*NPTS + n0 + l4*4] = raw;
      cs += __shfl_xor(cs, 16);
      cs += __shfl_xor(cs, 32);
      if (l4 == 0) atomicAdd(&colsum[(long long)z*NPTS + k], cs);
    }
  }
}

// ---------- finalize GN stats ----------
__global__ void fin_stats(float* __restrict__ part, float* __restrict__ stats,
                          long long slotStride, int G, float invGS)
{
  const int g = threadIdx.x;
  float* p  = part  + (long long)blockIdx.x * slotStride;
  float* st = stats + (long long)blockIdx.x * slotStride;
  if (g < G) {
    const float mu  = p[2*g] * invGS;
    const float var = p[2*g+1] * invGS - mu*mu;
    st[2*g]   = mu;
    st[2*g+1] = rsqrtf(var + 1e-5f);
    p[2*g] = 0.f; p[2*g+1] = 0.f;
  }
}

// ---------- gn+relu on POOLt [4][NPTS][192] ----------
__global__ __launch_bounds__(256) void gn_pool(float* __restrict__ pool,
    const float* __restrict__ stats, const float* __restrict__ w, const float* __restrict__ b)
{
  const int i = blockIdx.x*256 + threadIdx.x;
  const int z = i / (NPTS*192);
  const int c = i % 192;
  const int g = c >> 5;
  const float* st = stats + z*64;
  const float v = (pool[i] - st[2*g]) * st[2*g+1] * w[c] + b[c];
  pool[i] = fmaxf(v, 0.f);
}

// ---------- FEATS slot[n][c] = xin[n][c] + relu(gn(t[n][c])) ----------
__global__ __launch_bounds__(256) void gn_resid(const float* __restrict__ t,
    const float* __restrict__ xin, long long xZ, long long xld,
    const float* __restrict__ stats,
    const float* __restrict__ w, const float* __restrict__ b,
    float* __restrict__ outp, long long oZ)
{
  const int i = blockIdx.x*256 + threadIdx.x;
  const int z = blockIdx.y;
  const int n = i / 192, c = i % 192, g = c >> 5;
  const float* st = stats + z*16;
  const float v = (t[(long long)z*NPTS*192 + i] - st[2*g]) * st[2*g+1] * w[c] + b[c];
  outp[(long long)z*oZ + (long long)n*768 + c] =
      xin[(long long)z*xZ + (long long)n*xld + c] + fmaxf(v, 0.f);
}

// ---------- transpose -> bf16: src[z][R][C] -> dst[z][C][R] ----------
template<int SRCF32>
__global__ __launch_bounds__(256) void tr2bf(const void* __restrict__ src, short* __restrict__ dst,
                                             long long sZ, long long dZ, int R, int C)
{
  __shared__ float t[32][33];
  const int z = blockIdx.z;
  const int c0 = blockIdx.x*32, r0 = blockIdx.y*32;
  const int tx = threadIdx.x % 32, ty = threadIdx.x / 32;
  #pragma unroll
  for (int j = 0; j < 4; ++j) {
    const int r = r0 + ty + j*8;
    const long long idx = (long long)z*sZ + (long long)r*C + c0 + tx;
    t[ty + j*8][tx] = SRCF32 ? ((const float*)src)[idx] : b2f(((const short*)src)[idx]);
  }
  __syncthreads();
  #pragma unroll
  for (int j = 0; j < 4; ++j) {
    const int c = c0 + ty + j*8;
    dst[(long long)z*dZ + (long long)c*R + r0 + tx] = f2b(t[tx][ty + j*8]);
  }
}

// 1/(1e-9+s) -> o; zero s for next use
__global__ __launch_bounds__(256) void recip_zero(float* __restrict__ s, float* __restrict__ o, int n)
{ const int i = blockIdx.x*256 + threadIdx.x; if (i < n) { o[i] = 1.0f/(1e-9f + s[i]); s[i] = 0.f; } }

// ---------- fuse epilogue: GN(16x48) + leaky(0.2) + L2 norm ----------
__global__ __launch_bounds__(256) void finalize_gn(const float* __restrict__ fused,
    const float* __restrict__ stats, const float* __restrict__ w, const float* __restrict__ b,
    float* __restrict__ outp, long long oZ)
{
  const int n = blockIdx.x, z = blockIdx.y, tid = threadIdx.x;
  const float* fz = fused + ((long long)z*NPTS + n)*768;
  const float* st = stats + z*32;
  __shared__ float vbuf[768];
  __shared__ float red[256];
  float ss = 0.f;
  for (int c = tid; c < 768; c += 256) {
    float v = fz[c];
    const int g = c / 48;
    v = (v - st[2*g]) * st[2*g+1] * w[c] + b[c];
    v = v > 0.f ? v : 0.2f * v;
    vbuf[c] = v;
    ss = fmaf(v, v, ss);
  }
  red[tid] = ss; __syncthreads();
  for (int st_ = 128; st_; st_ >>= 1) { if (tid < st_) red[tid] += red[tid+st_]; __syncthreads(); }
  const float inv = 1.0f / (sqrtf(red[0]) + 1e-8f);
  float* ob = outp + (long long)z*oZ + (long long)n*768;
  for (int c = tid; c < 768; c += 256) ob[c] = vbuf[c] * inv;
}

extern "C" void kernel_launch(void* const* d_in, const int* in_sizes, int n_in,
                              void* d_out, int out_size, void* d_ws, size_t ws_size,
                              hipStream_t stream)
{
  const float* src = (const float*)d_in[0];
  const float* tgt = (const float*)d_in[1];
  const float* lfw[3]  = {(const float*)d_in[5], (const float*)d_in[8],  (const float*)d_in[11]};
  const float* lfgw[3] = {(const float*)d_in[6], (const float*)d_in[9],  (const float*)d_in[12]};
  const float* lfgb[3] = {(const float*)d_in[7], (const float*)d_in[10], (const float*)d_in[13]};
  const float* qk_w = (const float*)d_in[14];
  const float* v_w  = (const float*)d_in[15];
  const float* v_b  = (const float*)d_in[16];
  const float* t_w  = (const float*)d_in[17];
  const float* t_b  = (const float*)d_in[18];
  const float* bgw  = (const float*)d_in[19];
  const float* bgb  = (const float*)d_in[20];
  const float* fw   = (const float*)d_in[21];
  const float* fgw  = (const float*)d_in[22];
  const float* fgb  = (const float*)d_in[23];
  float* dout = (float*)d_out;

  const size_t availFl = ws_size / sizeof(float);
  float* ws = (float*)d_ws;
  size_t off = 0;
  float* POOLt = ws + off; off += (size_t)4*NPTS*192;     // [4][n][192]
  float* PART  = ws + off; off += 1024;
  float* STATS = ws + off; off += 1024;
  float* SB    = ws + off; off += (size_t)4*NPTS;
  float* SINV  = ws + off; off += (size_t)4*NPTS;
  // bf16 weights (lfw0b padded to K=32; qkwb padded to 64 rows/head)
  short* wreg = (short*)(ws + off);
  short* lfw0b = wreg;              // 128x32
  short* lfw1b = lfw0b + 4096;      // 256x128
  short* lfw2b = lfw1b + 32768;     // 192x256
  short* qkwb  = lfw2b + 49152;     // 4x64x192 (padded)
  short* vwb   = qkwb + 49152;      // 4x192x192
  short* twb   = vwb + 147456;      // 4x192x192
  short* fwb   = twb + 147456;      // 768x768
  off += (4096+32768+49152+49152+147456+147456+589824 + 1)/2 + 8;
  short* FEATb = (short*)(ws + off); off += (size_t)4*SPC*8/2;  // [4][k*NPTS+m][8]
  off = (off + 63) & ~(size_t)63;
  float* REG = ws + off;
  const size_t regAvail = (availFl > off) ? (availFl - off) : 0;

  // attention batching: XRt+Tt+FUSED + (QKT[.][64]+Vt+Vc)/2 + ATTB/2 per z
  const size_t perZ = 4915200;
  int nz;
  if      (regAvail >= 4*perZ) nz = 4;
  else if (regAvail >= 2*perZ) nz = 2;
  else if (regAvail >= perZ)   nz = 1;
  else return;

  // attn view of REG
  float* XRt   = REG;                               // [nz][n][192]
  float* Tt    = XRt + (size_t)nz*NPTS*192;         // [nz][n][192]
  float* FUSED = Tt  + (size_t)nz*NPTS*192;         // [nz][n][768]
  short* QKT   = (short*)(FUSED + (size_t)nz*NPTS*768);  // [nz][n][64]
  short* Vt    = QKT + (size_t)nz*NPTS*64;          // [nz][n][192]
  short* Vc    = Vt  + (size_t)nz*NPTS*192;         // [nz][192][n]
  short* ATTB  = Vc  + (size_t)nz*NPTS*192;         // [nz][m][n]

  dim3 b256(256);
  const float invConv = 1.0f / (32.0f * (float)SPC);

  cvt_w<<<dim3(16),  b256, 0, stream>>>(lfw[0], lfw0b, 128, 6, 32);
  cvt_w<<<dim3(128), b256, 0, stream>>>(lfw[1], lfw1b, 256, 128, 128);
  cvt_w<<<dim3(192), b256, 0, stream>>>(lfw[2], lfw2b, 192, 256, 256);
  fill0<<<dim3(96), b256, 0, stream>>>((float*)qkwb, 24576);   // zero the padded qk weights
  for (int i = 0; i < 4; ++i)
    cvt_w<<<dim3(36), b256, 0, stream>>>(qk_w + (size_t)i*48*192, qkwb + (size_t)i*64*192, 48, 192, 192);
  cvt_w<<<dim3(576), b256, 0, stream>>>(v_w,  vwb,  768, 192, 192);
  cvt_w<<<dim3(576), b256, 0, stream>>>(t_w,  twb,  768, 192, 192);
  cvt_w<<<dim3(2304),b256, 0, stream>>>(fw,   fwb,  768, 768, 768);
  fill0<<<dim3(4), b256, 0, stream>>>(PART, 1024);
  fill0<<<dim3(32), b256, 0, stream>>>(SB, 4*NPTS);

  // ---- ball query ----
  bq_feat<<<dim3(NPTS/4, 4), b256, 0, stream>>>(src, tgt, FEATb);

  // ---- fused conv tower: 3 stats passes, no HBM intermediates ----
  convfused<0><<<dim3(128, 1, 4), b256, 0, stream>>>(
      FEATb, lfw0b, nullptr, nullptr,
      nullptr, nullptr, nullptr, nullptr, nullptr, nullptr,
      nullptr, PART, 64);
  fin_stats<<<4, 32, 0, stream>>>(PART, STATS, 64, 4, invConv);
  convfused<1><<<dim3(128, 1, 4), b256, 0, stream>>>(
      FEATb, lfw0b, lfw1b, nullptr,
      STATS, lfgw[0], lfgb[0], nullptr, nullptr, nullptr,
      nullptr, PART+256, 64);
  fin_stats<<<4, 32, 0, stream>>>(PART+256, STATS+256, 64, 8, invConv);
  convfused<2><<<dim3(128, 1, 4), b256, 0, stream>>>(
      FEATb, lfw0b, lfw1b, lfw2b,
      STATS, lfgw[0], lfgb[0], STATS+256, lfgw[1], lfgb[1],
      POOLt, PART+512, 64);
  fin_stats<<<4, 32, 0, stream>>>(PART+512, STATS+512, 64, 6, invConv);
  gn_pool<<<dim3(4*NPTS*192/256), b256, 0, stream>>>(POOLt, STATS+512, lfgw[2], lfgb[2]);

  // ---- attention + fuse, nz clouds per batch ----
  for (int bb0 = 0; bb0 < 4; bb0 += nz) {
    for (int i = 0; i < 4; ++i) {
      const float* Xin; long long xZ, xld;
      if (i == 0) { Xin = POOLt + (size_t)bb0*NPTS*192; xZ = (long long)NPTS*192; xld = 192; }
      else        { Xin = dout + (size_t)bb0*NPTS*768 + (size_t)(i-1)*192; xZ = (long long)NPTS*768; xld = 768; }
      // qk -> QKT [n][64] bf16 (cols 48..63 zero via padded weights)
      mm<0><<<dim3(16, 1, nz), b256, 0, stream>>>(
          Xin, xld, xZ, nullptr,0,0,
          qkwb + (size_t)i*64*192, 0, QKT, 64, (long long)NPTS*64, 1,
          nullptr, nullptr,0, nullptr,0,nullptr,nullptr,
          nullptr, 0, 1, 64, 192, NPTS);
      // v -> Vt [n][192] bf16 (+bias)
      mm<0><<<dim3(16, 3, nz), b256, 0, stream>>>(
          Xin, xld, xZ, nullptr,0,0,
          vwb + (size_t)i*192*192, 0, Vt, 192, (long long)NPTS*192, 1,
          v_b + (size_t)i*192, nullptr,0, nullptr,0,nullptr,nullptr,
          nullptr, 0, 1, 192, 192, NPTS);
      // fused QK^T + softmax -> ATTB bf16 [m][n] + column sums into SB
      attn_fused<<<dim3(NPTS/16, nz), b256, 0, stream>>>(QKT, ATTB, SB);
      recip_zero<<<dim3(nz*NPTS/256), b256, 0, stream>>>(SB, SINV, nz*NPTS);
      tr2bf<0><<<dim3(6, 64, nz), b256, 0, stream>>>(Vt, Vc,
          (long long)NPTS*192, (long long)192*NPTS, NPTS, 192);
      // x_r^T [m][192] = (ATTB . Vc^T) * sinv[m]
      mm<1><<<dim3(16, 3, nz), b256, 0, stream>>>(
          ATTB, NPTS, (long long)NPTS*NPTS, nullptr,0,0,
          Vc, (long long)192*NPTS, XRt, 192, (long long)NPTS*192, 0,
          nullptr, SINV, NPTS, nullptr,0,nullptr,nullptr,
          nullptr, 0, 1, 192, NPTS, NPTS);
      // t [n][192] = (x - x_r) . t_w^T + t_b, + stats
      mm<0><<<dim3(16, 3, nz), b256, 0, stream>>>(
          Xin, xld, xZ, XRt, 192, (long long)NPTS*192,
          twb + (size_t)i*192*192, 0, Tt, 192, (long long)NPTS*192, 0,
          t_b + (size_t)i*192, nullptr,0, nullptr,0,nullptr,nullptr,
          PART+768, 16, 32, 192, 192, NPTS);
      fin_stats<<<nz, 32, 0, stream>>>(PART+768, STATS+768, 16, 6, 1.0f/65536.0f);
      gn_resid<<<dim3(NPTS*192/256, nz), b256, 0, stream>>>(
          Tt, Xin, xZ, xld, STATS+768,
          bgw + (size_t)i*192, bgb + (size_t)i*192,
          dout + (size_t)bb0*NPTS*768 + (size_t)i*192, (long long)NPTS*768);
    }
    // fuse
    mm<0><<<dim3(16, 12, nz), b256, 0, stream>>>(
        dout + (size_t)bb0*NPTS*768, 768, (long long)NPTS*768, nullptr,0,0,
        fwb, 0, FUSED, 768, (long long)NPTS*768, 0,
        nullptr, nullptr,0, nullptr,0,nullptr,nullptr,
        PART+832, 32, 48, 768, 768, NPTS);
    fin_stats<<<nz, 32, 0, stream>>>(PART+832, STATS+832, 32, 16, 1.0f/98304.0f);
    finalize_gn<<<dim3(NPTS, nz), b256, 0, stream>>>(
        FUSED, STATS+832, fgw, fgb,
        dout + (size_t)bb0*NPTS*768, (long long)NPTS*768);
  }
}